// Round 1
// baseline (2462.237 us; speedup 1.0000x reference)
//
#include <hip/hip_runtime.h>
#include <hip/hip_bf16.h>
#include <math.h>

// D=64, H=4 are compile-time; N, E, V read from in_sizes.
#define DD 64
#define HH 4
#define NEG_SLOPE 0.2f

__device__ __forceinline__ void atomicMaxF(float* addr, float val) {
    if (val >= 0.f) {
        atomicMax((int*)addr, __float_as_int(val));
    } else {
        atomicMin((unsigned int*)addr, __float_as_uint(val));
    }
}

__device__ __forceinline__ void atomAddF(float* a, float v) {
    unsafeAtomicAdd(a, v);  // global_atomic_add_f32 on gfx950
}

// ---------------------------------------------------------------------------
// Wc[type][h][i][d] = sum_f W[i, h*64+f] * Wsrc[h, f, d]   (fold node GEMM
// with the top half of the per-head source transform)
// ---------------------------------------------------------------------------
__global__ __launch_bounds__(256) void k_fold_mats(
        const float* __restrict__ W_a, const float* __restrict__ Wsrc_ab,
        const float* __restrict__ W_b, const float* __restrict__ Wsrc_ba,
        float* __restrict__ Wc_a, float* __restrict__ Wc_b) {
    int idx = blockIdx.x * 256 + threadIdx.x;   // 0 .. 2*H*64*64-1 = 32767
    int type = idx >> 14;
    int r = idx & 16383;
    int h = r >> 12;
    int i = (r >> 6) & 63;
    int d = r & 63;
    const float* W  = type ? W_b : W_a;
    const float* Ws = type ? Wsrc_ba : Wsrc_ab;
    float* out = type ? Wc_b : Wc_a;
    float acc = 0.f;
#pragma unroll 8
    for (int f = 0; f < DD; ++f)
        acc += W[i * (DD * HH) + h * DD + f] * Ws[h * (2 * DD * DD) + f * DD + d];
    out[r] = acc;
}

// ---------------------------------------------------------------------------
// Per-direction small folds:
//   mt[t,h,d]  = sum_f te[t,f] * Wsrc[h, D+f, d]          (type message)
//   bc[h,d]    = sum_f b_src[h*64+f] * Wsrc[h, f, d]      (bias for M)
//   st[t,h]    = sum_f te[t,f] * (Wsrc_bot@asrc + Wdst_bot@adst)[h,f]
//   wdst[h,i]  = sum_f W_dst[i, h*64+f] * (Wdst_top@adst)[h,f]
//   bdst[h]    = sum_f b_dst[h*64+f] * (Wdst_top@adst)[h,f]
// ---------------------------------------------------------------------------
__global__ __launch_bounds__(256) void k_fold_misc(
        const float* __restrict__ b_src,
        const float* __restrict__ Wsrc, const float* __restrict__ asrc,
        const float* __restrict__ W_dst, const float* __restrict__ b_dst,
        const float* __restrict__ Wdst, const float* __restrict__ adst,
        const float* __restrict__ te, int V,
        float* __restrict__ bc, float* __restrict__ st, float* __restrict__ mt,
        float* __restrict__ wdst, float* __restrict__ bdst) {
    int idx = blockIdx.x * 256 + threadIdx.x;
    const int S2 = 2 * DD * DD;  // stride of Wsrc/Wdst per head
    int mtN = V * HH * DD;
    if (idx < mtN) {                     // mt[t*256 + h*64 + d]
        int t = idx >> 8, h = (idx >> 6) & 3, d = idx & 63;
        float acc = 0.f;
        for (int f = 0; f < DD; ++f)
            acc += te[t * DD + f] * Wsrc[h * S2 + (DD + f) * DD + d];
        mt[idx] = acc;
        return;
    }
    idx -= mtN;
    if (idx < HH * DD) {                 // bc[h*64+d]
        int h = idx >> 6, d = idx & 63;
        float acc = 0.f;
        for (int f = 0; f < DD; ++f)
            acc += b_src[h * DD + f] * Wsrc[h * S2 + f * DD + d];
        bc[idx] = acc;
        return;
    }
    idx -= HH * DD;
    if (idx < V * HH) {                  // st[t*4+h]
        int t = idx >> 2, h = idx & 3;
        float acc = 0.f;
        for (int f = 0; f < DD; ++f) {
            float vs = 0.f, vd = 0.f;
            for (int d = 0; d < DD; ++d) {
                vs += Wsrc[h * S2 + (DD + f) * DD + d] * asrc[h * DD + d];
                vd += Wdst[h * S2 + (DD + f) * DD + d] * adst[h * DD + d];
            }
            acc += te[t * DD + f] * (vs + vd);
        }
        st[idx] = acc;
        return;
    }
    idx -= V * HH;
    if (idx < HH * DD) {                 // wdst[h*64+i]
        int h = idx >> 6, i = idx & 63;
        float acc = 0.f;
        for (int f = 0; f < DD; ++f) {
            float u = 0.f;
            for (int d = 0; d < DD; ++d)
                u += Wdst[h * S2 + f * DD + d] * adst[h * DD + d];
            acc += W_dst[i * (DD * HH) + h * DD + f] * u;
        }
        wdst[idx] = acc;
        return;
    }
    idx -= HH * DD;
    if (idx < HH) {                      // bdst[h]
        int h = idx;
        float acc = 0.f;
        for (int f = 0; f < DD; ++f) {
            float u = 0.f;
            for (int d = 0; d < DD; ++d)
                u += Wdst[h * S2 + f * DD + d] * adst[h * DD + d];
            acc += b_dst[h * DD + f] * u;
        }
        bdst[h] = acc;
    }
}

// ---------------------------------------------------------------------------
// Per node (one block = one node, wave w = head w):
//   M[n,h,d]  = sum_i x[n,i]*Wc[h,i,d] + bc[h,d]
//   ssrc[n,h] = M[n,h,:] . asrc[h]
//   sdst[n,h] = x[n,:] . wdst[h,:] + bdst[h]
// ---------------------------------------------------------------------------
__global__ __launch_bounds__(256) void k_node_transform(
        const float* __restrict__ x, const float* __restrict__ Wc,
        const float* __restrict__ bc, const float* __restrict__ asrc,
        const float* __restrict__ wdst, const float* __restrict__ bdst,
        float* __restrict__ M, float* __restrict__ ssrc, float* __restrict__ sdst) {
    int n = blockIdx.x;
    int t = threadIdx.x;
    int h = t >> 6, d = t & 63;
    __shared__ float xs[DD];
    if (t < DD) xs[t] = x[n * DD + t];
    __syncthreads();
    float acc = bc[h * DD + d];
#pragma unroll 8
    for (int f = 0; f < DD; ++f)
        acc += xs[f] * Wc[h * (DD * DD) + f * DD + d];
    M[(size_t)n * (HH * DD) + h * DD + d] = acc;
    float p = acc * asrc[h * DD + d];
    float q = xs[d] * wdst[h * DD + d];
#pragma unroll
    for (int off = 32; off; off >>= 1) {
        p += __shfl_xor(p, off, 64);
        q += __shfl_xor(q, off, 64);
    }
    if (d == 0) {
        ssrc[n * HH + h] = p;
        sdst[n * HH + h] = q + bdst[h];
    }
}

// ---------------------------------------------------------------------------
// Zero output accumulators / denominators, set running max to -inf.
// ---------------------------------------------------------------------------
__global__ void k_init(float* __restrict__ dout, float* __restrict__ den_a,
                       float* __restrict__ den_b, float* __restrict__ mx_a,
                       float* __restrict__ mx_b, int NH, size_t nout) {
    size_t i = (size_t)blockIdx.x * 256 + threadIdx.x;
    if (i < nout) dout[i] = 0.f;
    if (i < (size_t)NH) {
        den_a[i] = 0.f; den_b[i] = 0.f;
        mx_a[i] = -INFINITY; mx_b[i] = -INFINITY;
    }
}

// ---------------------------------------------------------------------------
// Pass 1 over edges: logit + segment-max (atomic float max).
// ---------------------------------------------------------------------------
__global__ __launch_bounds__(256) void k_edge_logits(
        const int* __restrict__ ei, const int* __restrict__ et,
        const float* __restrict__ ssrc, const float* __restrict__ sdst,
        const float* __restrict__ st, float* __restrict__ logit,
        float* __restrict__ mx, int E) {
    int e = blockIdx.x * 256 + threadIdx.x;
    if (e >= E) return;
    int s = ei[e], dv = ei[E + e], t = et[e];
    float4 a = ((const float4*)ssrc)[s];
    float4 b = ((const float4*)sdst)[dv];
    float4 c = ((const float4*)st)[t];
    float4 l;
    l.x = a.x + b.x + c.x;  l.x = l.x > 0.f ? l.x : NEG_SLOPE * l.x;
    l.y = a.y + b.y + c.y;  l.y = l.y > 0.f ? l.y : NEG_SLOPE * l.y;
    l.z = a.z + b.z + c.z;  l.z = l.z > 0.f ? l.z : NEG_SLOPE * l.z;
    l.w = a.w + b.w + c.w;  l.w = l.w > 0.f ? l.w : NEG_SLOPE * l.w;
    ((float4*)logit)[e] = l;
    atomicMaxF(&mx[dv * 4 + 0], l.x);
    atomicMaxF(&mx[dv * 4 + 1], l.y);
    atomicMaxF(&mx[dv * 4 + 2], l.z);
    atomicMaxF(&mx[dv * 4 + 3], l.w);
}

// ---------------------------------------------------------------------------
// Pass 2 over edges: one wave per (edge, head).
//   ex = exp(l - mx[dst,h]); den[dst,h] += ex;
//   num[dst,h,:] += ex * (M[src,h,:] + mt[type,h,:])
// ---------------------------------------------------------------------------
__global__ __launch_bounds__(256) void k_edge_accum(
        const int* __restrict__ ei, const int* __restrict__ et,
        const float* __restrict__ logit, const float* __restrict__ mx,
        const float* __restrict__ M, const float* __restrict__ mt,
        float* __restrict__ den, float* __restrict__ num, int E) {
    int w = blockIdx.x * 4 + (threadIdx.x >> 6);
    int lane = threadIdx.x & 63;
    int e = w >> 2, h = w & 3;
    if (e >= E) return;
    int s = ei[e], dv = ei[E + e], t = et[e];
    float ex = __expf(logit[e * 4 + h] - mx[dv * 4 + h]);
    if (lane == 0) atomAddF(&den[dv * 4 + h], ex);
    float msg = M[(size_t)s * (HH * DD) + h * DD + lane] + mt[t * (HH * DD) + h * DD + lane];
    atomAddF(&num[(size_t)dv * (HH * DD) + h * DD + lane], ex * msg);
}

// ---------------------------------------------------------------------------
// out = elu(num / (den + 1e-16)), in place on d_out.
// ---------------------------------------------------------------------------
__global__ __launch_bounds__(256) void k_finalize(
        float* __restrict__ dout, const float* __restrict__ den_a,
        const float* __restrict__ den_b, size_t NHD) {
    size_t i = (size_t)blockIdx.x * 256 + threadIdx.x;
    if (i >= 2 * NHD) return;
    int side = i >= NHD;
    size_t r = side ? i - NHD : i;
    int nh = (int)(r >> 6);  // n*4 + h
    const float* den = side ? den_b : den_a;
    float v = dout[i] / (den[nh] + 1e-16f);
    dout[i] = v > 0.f ? v : expm1f(v);
}

// ---------------------------------------------------------------------------
extern "C" void kernel_launch(void* const* d_in, const int* in_sizes, int n_in,
                              void* d_out, int out_size, void* d_ws, size_t ws_size,
                              hipStream_t stream) {
    const float* x_a     = (const float*)d_in[0];
    const float* x_b     = (const float*)d_in[1];
    const float* W_a     = (const float*)d_in[2];
    const float* b_a     = (const float*)d_in[3];
    const float* W_b     = (const float*)d_in[4];
    const float* b_b     = (const float*)d_in[5];
    const float* te      = (const float*)d_in[6];
    const float* Wsrc_ab = (const float*)d_in[7];
    const float* Wdst_ab = (const float*)d_in[8];
    const float* asrc_ab = (const float*)d_in[9];
    const float* adst_ab = (const float*)d_in[10];
    const float* Wsrc_ba = (const float*)d_in[11];
    const float* Wdst_ba = (const float*)d_in[12];
    const float* asrc_ba = (const float*)d_in[13];
    const float* adst_ba = (const float*)d_in[14];
    const int*   ei_ab   = (const int*)d_in[15];
    const int*   et_ab   = (const int*)d_in[16];
    const int*   ei_ba   = (const int*)d_in[17];
    const int*   et_ba   = (const int*)d_in[18];
    float* dout = (float*)d_out;

    int N = in_sizes[0] / DD;
    int E = in_sizes[15] / 2;
    int V = in_sizes[6] / DD;

    // workspace carve-up (all offsets 64-element = 256B aligned)
    float* p = (float*)d_ws;
    auto alloc = [&](size_t n) { float* r = p; p += (n + 63) & ~(size_t)63; return r; };
    float* M_a      = alloc((size_t)N * HH * DD);
    float* M_b      = alloc((size_t)N * HH * DD);
    float* ssrc_a   = alloc((size_t)N * HH);
    float* sdst_a   = alloc((size_t)N * HH);
    float* ssrc_b   = alloc((size_t)N * HH);
    float* sdst_b   = alloc((size_t)N * HH);
    float* st_ab    = alloc(V * HH);
    float* st_ba    = alloc(V * HH);
    float* mt_ab    = alloc(V * HH * DD);
    float* mt_ba    = alloc(V * HH * DD);
    float* Wc_a     = alloc(HH * DD * DD);
    float* Wc_b     = alloc(HH * DD * DD);
    float* bc_a     = alloc(HH * DD);
    float* bc_b     = alloc(HH * DD);
    float* wdst_a   = alloc(HH * DD);
    float* wdst_b   = alloc(HH * DD);
    float* bdst_a   = alloc(HH);
    float* bdst_b   = alloc(HH);
    float* logit_ab = alloc((size_t)E * HH);
    float* logit_ba = alloc((size_t)E * HH);
    float* mx_a     = alloc((size_t)N * HH);
    float* mx_b     = alloc((size_t)N * HH);
    float* den_a    = alloc((size_t)N * HH);
    float* den_b    = alloc((size_t)N * HH);

    // 1. fold weights
    k_fold_mats<<<(2 * HH * DD * DD + 255) / 256, 256, 0, stream>>>(
        W_a, Wsrc_ab, W_b, Wsrc_ba, Wc_a, Wc_b);
    int miscTot = V * HH * DD + HH * DD + V * HH + HH * DD + HH;
    int miscBlocks = (miscTot + 255) / 256;
    // direction AB: src=a, dst=b
    k_fold_misc<<<miscBlocks, 256, 0, stream>>>(
        b_a, Wsrc_ab, asrc_ab, W_b, b_b, Wdst_ab, adst_ab, te, V,
        bc_a, st_ab, mt_ab, wdst_b, bdst_b);
    // direction BA: src=b, dst=a
    k_fold_misc<<<miscBlocks, 256, 0, stream>>>(
        b_b, Wsrc_ba, asrc_ba, W_a, b_a, Wdst_ba, adst_ba, te, V,
        bc_b, st_ba, mt_ba, wdst_a, bdst_a);

    // 2. init accumulators
    size_t nout = (size_t)2 * N * HH * DD;
    k_init<<<(int)((nout + 255) / 256), 256, 0, stream>>>(
        dout, den_a, den_b, mx_a, mx_b, N * HH, nout);

    // 3. node transforms (M, ssrc, sdst)
    k_node_transform<<<N, 256, 0, stream>>>(
        x_a, Wc_a, bc_a, asrc_ab, wdst_a, bdst_a, M_a, ssrc_a, sdst_a);
    k_node_transform<<<N, 256, 0, stream>>>(
        x_b, Wc_b, bc_b, asrc_ba, wdst_b, bdst_b, M_b, ssrc_b, sdst_b);

    // 4. edge logits + segment max
    k_edge_logits<<<(E + 255) / 256, 256, 0, stream>>>(
        ei_ab, et_ab, ssrc_a, sdst_b, st_ab, logit_ab, mx_b, E);
    k_edge_logits<<<(E + 255) / 256, 256, 0, stream>>>(
        ei_ba, et_ba, ssrc_b, sdst_a, st_ba, logit_ba, mx_a, E);

    // 5. exp + weighted scatter (accumulate straight into d_out)
    k_edge_accum<<<E, 256, 0, stream>>>(
        ei_ab, et_ab, logit_ab, mx_b, M_a, mt_ab, den_b, dout + (size_t)N * HH * DD, E);
    k_edge_accum<<<E, 256, 0, stream>>>(
        ei_ba, et_ba, logit_ba, mx_a, M_b, mt_ba, den_a, dout, E);

    // 6. normalize + ELU in place
    k_finalize<<<(int)((nout + 255) / 256), 256, 0, stream>>>(
        dout, den_a, den_b, (size_t)N * HH * DD);
}

// Round 2
// 1567.495 us; speedup vs baseline: 1.5708x; 1.5708x over previous
//
#include <hip/hip_runtime.h>
#include <hip/hip_bf16.h>
#include <math.h>

// D=64, H=4 are compile-time; N, E, V read from in_sizes.
#define DD 64
#define HH 4
#define NEG_SLOPE 0.2f

__device__ __forceinline__ void atomicMaxF(float* addr, float val) {
    if (val >= 0.f) {
        atomicMax((int*)addr, __float_as_int(val));
    } else {
        atomicMin((unsigned int*)addr, __float_as_uint(val));
    }
}

__device__ __forceinline__ void atomAddF(float* a, float v) {
    unsafeAtomicAdd(a, v);  // global_atomic_add_f32 on gfx950
}

// ---------------------------------------------------------------------------
// Wc[type][h][i][d] = sum_f W[i, h*64+f] * Wsrc[h, f, d]   (fold node GEMM
// with the top half of the per-head source transform)
// ---------------------------------------------------------------------------
__global__ __launch_bounds__(256) void k_fold_mats(
        const float* __restrict__ W_a, const float* __restrict__ Wsrc_ab,
        const float* __restrict__ W_b, const float* __restrict__ Wsrc_ba,
        float* __restrict__ Wc_a, float* __restrict__ Wc_b) {
    int idx = blockIdx.x * 256 + threadIdx.x;   // 0 .. 2*H*64*64-1 = 32767
    int type = idx >> 14;
    int r = idx & 16383;
    int h = r >> 12;
    int i = (r >> 6) & 63;
    int d = r & 63;
    const float* W  = type ? W_b : W_a;
    const float* Ws = type ? Wsrc_ba : Wsrc_ab;
    float* out = type ? Wc_b : Wc_a;
    float acc = 0.f;
#pragma unroll 8
    for (int f = 0; f < DD; ++f)
        acc += W[i * (DD * HH) + h * DD + f] * Ws[h * (2 * DD * DD) + f * DD + d];
    out[r] = acc;
}

// ---------------------------------------------------------------------------
// Precompute per-direction attention-fold vectors (one thread per output,
// 64 MACs each — kills the O(64^2)-per-thread serial tail of round 0):
//   ub_s[h,f] = sum_d Wsrc[h, D+f, d] * asrc[h,d]   (bottom half of Wsrc . asrc)
//   ub_d[h,f] = sum_d Wdst[h, D+f, d] * adst[h,d]   (bottom half of Wdst . adst)
//   ut_d[h,f] = sum_d Wdst[h, f,   d] * adst[h,d]   (top half of Wdst . adst)
// ---------------------------------------------------------------------------
__global__ __launch_bounds__(256) void k_fold_u(
        const float* __restrict__ Wsrc, const float* __restrict__ asrc,
        const float* __restrict__ Wdst, const float* __restrict__ adst,
        float* __restrict__ ub_s, float* __restrict__ ub_d, float* __restrict__ ut_d) {
    int idx = blockIdx.x * 256 + threadIdx.x;  // 0 .. 3*H*D-1 = 767
    if (idx >= 3 * HH * DD) return;
    const int S2 = 2 * DD * DD;
    int kind = idx >> 8;
    int r = idx & 255;
    int h = r >> 6, f = r & 63;
    const float* Wm = (kind == 0) ? Wsrc : Wdst;
    const float* av = (kind == 0) ? asrc : adst;
    int row = (kind == 2) ? f : (DD + f);
    float acc = 0.f;
#pragma unroll 8
    for (int d = 0; d < DD; ++d)
        acc += Wm[h * S2 + row * DD + d] * av[h * DD + d];
    float* out = (kind == 0) ? ub_s : (kind == 1) ? ub_d : ut_d;
    out[r] = acc;
}

// ---------------------------------------------------------------------------
// Per-direction small folds — every output is now a single 64-MAC loop:
//   mt[t,h,d]  = sum_f te[t,f] * Wsrc[h, D+f, d]          (type message)
//   bc[h,d]    = sum_f b_src[h*64+f] * Wsrc[h, f, d]      (bias for M)
//   st[t,h]    = sum_f te[t,f] * (ub_s + ub_d)[h,f]
//   wdst[h,i]  = sum_f W_dst[i, h*64+f] * ut_d[h,f]
//   bdst[h]    = sum_f b_dst[h*64+f] * ut_d[h,f]
// ---------------------------------------------------------------------------
__global__ __launch_bounds__(256) void k_fold_misc(
        const float* __restrict__ b_src, const float* __restrict__ Wsrc,
        const float* __restrict__ W_dst, const float* __restrict__ b_dst,
        const float* __restrict__ te, int V,
        const float* __restrict__ ub_s, const float* __restrict__ ub_d,
        const float* __restrict__ ut_d,
        float* __restrict__ bc, float* __restrict__ st, float* __restrict__ mt,
        float* __restrict__ wdst, float* __restrict__ bdst) {
    int idx = blockIdx.x * 256 + threadIdx.x;
    const int S2 = 2 * DD * DD;  // stride of Wsrc/Wdst per head
    int mtN = V * HH * DD;
    if (idx < mtN) {                     // mt[t*256 + h*64 + d]
        int t = idx >> 8, h = (idx >> 6) & 3, d = idx & 63;
        float acc = 0.f;
#pragma unroll 8
        for (int f = 0; f < DD; ++f)
            acc += te[t * DD + f] * Wsrc[h * S2 + (DD + f) * DD + d];
        mt[idx] = acc;
        return;
    }
    idx -= mtN;
    if (idx < HH * DD) {                 // bc[h*64+d]
        int h = idx >> 6, d = idx & 63;
        float acc = 0.f;
#pragma unroll 8
        for (int f = 0; f < DD; ++f)
            acc += b_src[h * DD + f] * Wsrc[h * S2 + f * DD + d];
        bc[idx] = acc;
        return;
    }
    idx -= HH * DD;
    if (idx < V * HH) {                  // st[t*4+h]
        int t = idx >> 2, h = idx & 3;
        float acc = 0.f;
#pragma unroll 8
        for (int f = 0; f < DD; ++f)
            acc += te[t * DD + f] * (ub_s[h * DD + f] + ub_d[h * DD + f]);
        st[idx] = acc;
        return;
    }
    idx -= V * HH;
    if (idx < HH * DD) {                 // wdst[h*64+i]
        int h = idx >> 6, i = idx & 63;
        float acc = 0.f;
#pragma unroll 8
        for (int f = 0; f < DD; ++f)
            acc += W_dst[i * (DD * HH) + h * DD + f] * ut_d[h * DD + f];
        wdst[idx] = acc;
        return;
    }
    idx -= HH * DD;
    if (idx < HH) {                      // bdst[h]
        int h = idx;
        float acc = 0.f;
#pragma unroll 8
        for (int f = 0; f < DD; ++f)
            acc += b_dst[h * DD + f] * ut_d[h * DD + f];
        bdst[h] = acc;
    }
}

// ---------------------------------------------------------------------------
// Per node (one block = one node, wave w = head w):
//   M[n,h,d]  = sum_i x[n,i]*Wc[h,i,d] + bc[h,d]
//   ssrc[n,h] = M[n,h,:] . asrc[h]
//   sdst[n,h] = x[n,:] . wdst[h,:] + bdst[h]
// ---------------------------------------------------------------------------
__global__ __launch_bounds__(256) void k_node_transform(
        const float* __restrict__ x, const float* __restrict__ Wc,
        const float* __restrict__ bc, const float* __restrict__ asrc,
        const float* __restrict__ wdst, const float* __restrict__ bdst,
        float* __restrict__ M, float* __restrict__ ssrc, float* __restrict__ sdst) {
    int n = blockIdx.x;
    int t = threadIdx.x;
    int h = t >> 6, d = t & 63;
    __shared__ float xs[DD];
    if (t < DD) xs[t] = x[n * DD + t];
    __syncthreads();
    float acc = bc[h * DD + d];
#pragma unroll 8
    for (int f = 0; f < DD; ++f)
        acc += xs[f] * Wc[h * (DD * DD) + f * DD + d];
    M[(size_t)n * (HH * DD) + h * DD + d] = acc;
    float p = acc * asrc[h * DD + d];
    float q = xs[d] * wdst[h * DD + d];
#pragma unroll
    for (int off = 32; off; off >>= 1) {
        p += __shfl_xor(p, off, 64);
        q += __shfl_xor(q, off, 64);
    }
    if (d == 0) {
        ssrc[n * HH + h] = p;
        sdst[n * HH + h] = q + bdst[h];
    }
}

// ---------------------------------------------------------------------------
// Zero output accumulators / denominators, set running max to -inf.
// ---------------------------------------------------------------------------
__global__ void k_init(float* __restrict__ dout, float* __restrict__ den_a,
                       float* __restrict__ den_b, float* __restrict__ mx_a,
                       float* __restrict__ mx_b, int NH, size_t nout) {
    size_t i = (size_t)blockIdx.x * 256 + threadIdx.x;
    if (i < nout) dout[i] = 0.f;
    if (i < (size_t)NH) {
        den_a[i] = 0.f; den_b[i] = 0.f;
        mx_a[i] = -INFINITY; mx_b[i] = -INFINITY;
    }
}

// ---------------------------------------------------------------------------
// Pass 1 over edges: logit + segment-max (atomic float max).
// ---------------------------------------------------------------------------
__global__ __launch_bounds__(256) void k_edge_logits(
        const int* __restrict__ ei, const int* __restrict__ et,
        const float* __restrict__ ssrc, const float* __restrict__ sdst,
        const float* __restrict__ st, float* __restrict__ logit,
        float* __restrict__ mx, int E) {
    int e = blockIdx.x * 256 + threadIdx.x;
    if (e >= E) return;
    int s = ei[e], dv = ei[E + e], t = et[e];
    float4 a = ((const float4*)ssrc)[s];
    float4 b = ((const float4*)sdst)[dv];
    float4 c = ((const float4*)st)[t];
    float4 l;
    l.x = a.x + b.x + c.x;  l.x = l.x > 0.f ? l.x : NEG_SLOPE * l.x;
    l.y = a.y + b.y + c.y;  l.y = l.y > 0.f ? l.y : NEG_SLOPE * l.y;
    l.z = a.z + b.z + c.z;  l.z = l.z > 0.f ? l.z : NEG_SLOPE * l.z;
    l.w = a.w + b.w + c.w;  l.w = l.w > 0.f ? l.w : NEG_SLOPE * l.w;
    ((float4*)logit)[e] = l;
    atomicMaxF(&mx[dv * 4 + 0], l.x);
    atomicMaxF(&mx[dv * 4 + 1], l.y);
    atomicMaxF(&mx[dv * 4 + 2], l.z);
    atomicMaxF(&mx[dv * 4 + 3], l.w);
}

// ---------------------------------------------------------------------------
// Pass 2 over edges: one wave per (edge, head).
//   ex = exp(l - mx[dst,h]); den[dst,h] += ex;
//   num[dst,h,:] += ex * (M[src,h,:] + mt[type,h,:])
// ---------------------------------------------------------------------------
__global__ __launch_bounds__(256) void k_edge_accum(
        const int* __restrict__ ei, const int* __restrict__ et,
        const float* __restrict__ logit, const float* __restrict__ mx,
        const float* __restrict__ M, const float* __restrict__ mt,
        float* __restrict__ den, float* __restrict__ num, int E) {
    int w = blockIdx.x * 4 + (threadIdx.x >> 6);
    int lane = threadIdx.x & 63;
    int e = w >> 2, h = w & 3;
    if (e >= E) return;
    int s = ei[e], dv = ei[E + e], t = et[e];
    float ex = __expf(logit[e * 4 + h] - mx[dv * 4 + h]);
    if (lane == 0) atomAddF(&den[dv * 4 + h], ex);
    float msg = M[(size_t)s * (HH * DD) + h * DD + lane] + mt[t * (HH * DD) + h * DD + lane];
    atomAddF(&num[(size_t)dv * (HH * DD) + h * DD + lane], ex * msg);
}

// ---------------------------------------------------------------------------
// out = elu(num / (den + 1e-16)), in place on d_out.
// ---------------------------------------------------------------------------
__global__ __launch_bounds__(256) void k_finalize(
        float* __restrict__ dout, const float* __restrict__ den_a,
        const float* __restrict__ den_b, size_t NHD) {
    size_t i = (size_t)blockIdx.x * 256 + threadIdx.x;
    if (i >= 2 * NHD) return;
    int side = i >= NHD;
    size_t r = side ? i - NHD : i;
    int nh = (int)(r >> 6);  // n*4 + h
    const float* den = side ? den_b : den_a;
    float v = dout[i] / (den[nh] + 1e-16f);
    dout[i] = v > 0.f ? v : expm1f(v);
}

// ---------------------------------------------------------------------------
extern "C" void kernel_launch(void* const* d_in, const int* in_sizes, int n_in,
                              void* d_out, int out_size, void* d_ws, size_t ws_size,
                              hipStream_t stream) {
    const float* x_a     = (const float*)d_in[0];
    const float* x_b     = (const float*)d_in[1];
    const float* W_a     = (const float*)d_in[2];
    const float* b_a     = (const float*)d_in[3];
    const float* W_b     = (const float*)d_in[4];
    const float* b_b     = (const float*)d_in[5];
    const float* te      = (const float*)d_in[6];
    const float* Wsrc_ab = (const float*)d_in[7];
    const float* Wdst_ab = (const float*)d_in[8];
    const float* asrc_ab = (const float*)d_in[9];
    const float* adst_ab = (const float*)d_in[10];
    const float* Wsrc_ba = (const float*)d_in[11];
    const float* Wdst_ba = (const float*)d_in[12];
    const float* asrc_ba = (const float*)d_in[13];
    const float* adst_ba = (const float*)d_in[14];
    const int*   ei_ab   = (const int*)d_in[15];
    const int*   et_ab   = (const int*)d_in[16];
    const int*   ei_ba   = (const int*)d_in[17];
    const int*   et_ba   = (const int*)d_in[18];
    float* dout = (float*)d_out;

    int N = in_sizes[0] / DD;
    int E = in_sizes[15] / 2;
    int V = in_sizes[6] / DD;

    // workspace carve-up (all offsets 64-element = 256B aligned)
    float* p = (float*)d_ws;
    auto alloc = [&](size_t n) { float* r = p; p += (n + 63) & ~(size_t)63; return r; };
    float* M_a      = alloc((size_t)N * HH * DD);
    float* M_b      = alloc((size_t)N * HH * DD);
    float* ssrc_a   = alloc((size_t)N * HH);
    float* sdst_a   = alloc((size_t)N * HH);
    float* ssrc_b   = alloc((size_t)N * HH);
    float* sdst_b   = alloc((size_t)N * HH);
    float* st_ab    = alloc(V * HH);
    float* st_ba    = alloc(V * HH);
    float* mt_ab    = alloc(V * HH * DD);
    float* mt_ba    = alloc(V * HH * DD);
    float* Wc_a     = alloc(HH * DD * DD);
    float* Wc_b     = alloc(HH * DD * DD);
    float* bc_a     = alloc(HH * DD);
    float* bc_b     = alloc(HH * DD);
    float* wdst_a   = alloc(HH * DD);
    float* wdst_b   = alloc(HH * DD);
    float* bdst_a   = alloc(HH);
    float* bdst_b   = alloc(HH);
    float* ub_s_ab  = alloc(HH * DD);
    float* ub_d_ab  = alloc(HH * DD);
    float* ut_d_ab  = alloc(HH * DD);
    float* ub_s_ba  = alloc(HH * DD);
    float* ub_d_ba  = alloc(HH * DD);
    float* ut_d_ba  = alloc(HH * DD);
    float* logit_ab = alloc((size_t)E * HH);
    float* logit_ba = alloc((size_t)E * HH);
    float* mx_a     = alloc((size_t)N * HH);
    float* mx_b     = alloc((size_t)N * HH);
    float* den_a    = alloc((size_t)N * HH);
    float* den_b    = alloc((size_t)N * HH);

    // 1. fold weights
    k_fold_mats<<<(2 * HH * DD * DD + 255) / 256, 256, 0, stream>>>(
        W_a, Wsrc_ab, W_b, Wsrc_ba, Wc_a, Wc_b);
    // 1a. attention-fold vectors (parallel 64-MAC dots)
    k_fold_u<<<3, 256, 0, stream>>>(Wsrc_ab, asrc_ab, Wdst_ab, adst_ab,
                                    ub_s_ab, ub_d_ab, ut_d_ab);
    k_fold_u<<<3, 256, 0, stream>>>(Wsrc_ba, asrc_ba, Wdst_ba, adst_ba,
                                    ub_s_ba, ub_d_ba, ut_d_ba);
    int miscTot = V * HH * DD + HH * DD + V * HH + HH * DD + HH;
    int miscBlocks = (miscTot + 255) / 256;
    // direction AB: src=a, dst=b
    k_fold_misc<<<miscBlocks, 256, 0, stream>>>(
        b_a, Wsrc_ab, W_b, b_b, te, V, ub_s_ab, ub_d_ab, ut_d_ab,
        bc_a, st_ab, mt_ab, wdst_b, bdst_b);
    // direction BA: src=b, dst=a
    k_fold_misc<<<miscBlocks, 256, 0, stream>>>(
        b_b, Wsrc_ba, W_a, b_a, te, V, ub_s_ba, ub_d_ba, ut_d_ba,
        bc_b, st_ba, mt_ba, wdst_a, bdst_a);

    // 2. init accumulators
    size_t nout = (size_t)2 * N * HH * DD;
    k_init<<<(int)((nout + 255) / 256), 256, 0, stream>>>(
        dout, den_a, den_b, mx_a, mx_b, N * HH, nout);

    // 3. node transforms (M, ssrc, sdst)
    k_node_transform<<<N, 256, 0, stream>>>(
        x_a, Wc_a, bc_a, asrc_ab, wdst_a, bdst_a, M_a, ssrc_a, sdst_a);
    k_node_transform<<<N, 256, 0, stream>>>(
        x_b, Wc_b, bc_b, asrc_ba, wdst_b, bdst_b, M_b, ssrc_b, sdst_b);

    // 4. edge logits + segment max
    k_edge_logits<<<(E + 255) / 256, 256, 0, stream>>>(
        ei_ab, et_ab, ssrc_a, sdst_b, st_ab, logit_ab, mx_b, E);
    k_edge_logits<<<(E + 255) / 256, 256, 0, stream>>>(
        ei_ba, et_ba, ssrc_b, sdst_a, st_ba, logit_ba, mx_a, E);

    // 5. exp + weighted scatter (accumulate straight into d_out)
    k_edge_accum<<<E, 256, 0, stream>>>(
        ei_ab, et_ab, logit_ab, mx_b, M_a, mt_ab, den_b, dout + (size_t)N * HH * DD, E);
    k_edge_accum<<<E, 256, 0, stream>>>(
        ei_ba, et_ba, logit_ba, mx_a, M_b, mt_ba, den_a, dout, E);

    // 6. normalize + ELU in place
    k_finalize<<<(int)((nout + 255) / 256), 256, 0, stream>>>(
        dout, den_a, den_b, (size_t)N * HH * DD);
}

// Round 4
// 1119.430 us; speedup vs baseline: 2.1995x; 1.4003x over previous
//
#include <hip/hip_runtime.h>
#include <hip/hip_bf16.h>
#include <math.h>

// D=64, H=4 are compile-time; N, E, V read from in_sizes.
#define DD 64
#define HH 4
#define NEG_SLOPE 0.2f

// ---------------------------------------------------------------------------
// Wc[type][h][i][d] = sum_f W[i, h*64+f] * Wsrc[h, f, d]
// ---------------------------------------------------------------------------
__global__ __launch_bounds__(256) void k_fold_mats(
        const float* __restrict__ W_a, const float* __restrict__ Wsrc_ab,
        const float* __restrict__ W_b, const float* __restrict__ Wsrc_ba,
        float* __restrict__ Wc_a, float* __restrict__ Wc_b) {
    int idx = blockIdx.x * 256 + threadIdx.x;   // 0 .. 2*H*64*64-1 = 32767
    int type = idx >> 14;
    int r = idx & 16383;
    int h = r >> 12;
    int i = (r >> 6) & 63;
    int d = r & 63;
    const float* W  = type ? W_b : W_a;
    const float* Ws = type ? Wsrc_ba : Wsrc_ab;
    float* out = type ? Wc_b : Wc_a;
    float acc = 0.f;
#pragma unroll 8
    for (int f = 0; f < DD; ++f)
        acc += W[i * (DD * HH) + h * DD + f] * Ws[h * (2 * DD * DD) + f * DD + d];
    out[r] = acc;
}

// ---------------------------------------------------------------------------
//   ub_s[h,f] = sum_d Wsrc[h, D+f, d] * asrc[h,d]
//   ub_d[h,f] = sum_d Wdst[h, D+f, d] * adst[h,d]
//   ut_d[h,f] = sum_d Wdst[h, f,   d] * adst[h,d]
// ---------------------------------------------------------------------------
__global__ __launch_bounds__(256) void k_fold_u(
        const float* __restrict__ Wsrc, const float* __restrict__ asrc,
        const float* __restrict__ Wdst, const float* __restrict__ adst,
        float* __restrict__ ub_s, float* __restrict__ ub_d, float* __restrict__ ut_d) {
    int idx = blockIdx.x * 256 + threadIdx.x;  // 0 .. 3*H*D-1 = 767
    if (idx >= 3 * HH * DD) return;
    const int S2 = 2 * DD * DD;
    int kind = idx >> 8;
    int r = idx & 255;
    int h = r >> 6, f = r & 63;
    const float* Wm = (kind == 0) ? Wsrc : Wdst;
    const float* av = (kind == 0) ? asrc : adst;
    int row = (kind == 2) ? f : (DD + f);
    float acc = 0.f;
#pragma unroll 8
    for (int d = 0; d < DD; ++d)
        acc += Wm[h * S2 + row * DD + d] * av[h * DD + d];
    float* out = (kind == 0) ? ub_s : (kind == 1) ? ub_d : ut_d;
    out[r] = acc;
}

// ---------------------------------------------------------------------------
// Per-direction small folds — every output is a single 64-MAC loop.
// ---------------------------------------------------------------------------
__global__ __launch_bounds__(256) void k_fold_misc(
        const float* __restrict__ b_src, const float* __restrict__ Wsrc,
        const float* __restrict__ W_dst, const float* __restrict__ b_dst,
        const float* __restrict__ te, int V,
        const float* __restrict__ ub_s, const float* __restrict__ ub_d,
        const float* __restrict__ ut_d,
        float* __restrict__ bc, float* __restrict__ st, float* __restrict__ mt,
        float* __restrict__ wdst, float* __restrict__ bdst) {
    int idx = blockIdx.x * 256 + threadIdx.x;
    const int S2 = 2 * DD * DD;
    int mtN = V * HH * DD;
    if (idx < mtN) {                     // mt[t*256 + h*64 + d]
        int t = idx >> 8, h = (idx >> 6) & 3, d = idx & 63;
        float acc = 0.f;
#pragma unroll 8
        for (int f = 0; f < DD; ++f)
            acc += te[t * DD + f] * Wsrc[h * S2 + (DD + f) * DD + d];
        mt[idx] = acc;
        return;
    }
    idx -= mtN;
    if (idx < HH * DD) {                 // bc[h*64+d]
        int h = idx >> 6, d = idx & 63;
        float acc = 0.f;
#pragma unroll 8
        for (int f = 0; f < DD; ++f)
            acc += b_src[h * DD + f] * Wsrc[h * S2 + f * DD + d];
        bc[idx] = acc;
        return;
    }
    idx -= HH * DD;
    if (idx < V * HH) {                  // st[t*4+h]
        int t = idx >> 2, h = idx & 3;
        float acc = 0.f;
#pragma unroll 8
        for (int f = 0; f < DD; ++f)
            acc += te[t * DD + f] * (ub_s[h * DD + f] + ub_d[h * DD + f]);
        st[idx] = acc;
        return;
    }
    idx -= V * HH;
    if (idx < HH * DD) {                 // wdst[h*64+i]
        int h = idx >> 6, i = idx & 63;
        float acc = 0.f;
#pragma unroll 8
        for (int f = 0; f < DD; ++f)
            acc += W_dst[i * (DD * HH) + h * DD + f] * ut_d[h * DD + f];
        wdst[idx] = acc;
        return;
    }
    idx -= HH * DD;
    if (idx < HH) {                      // bdst[h]
        int h = idx;
        float acc = 0.f;
#pragma unroll 8
        for (int f = 0; f < DD; ++f)
            acc += b_dst[h * DD + f] * ut_d[h * DD + f];
        bdst[h] = acc;
    }
}

// ---------------------------------------------------------------------------
// Per node (one block = one node, wave w = head w):
//   M[n,h,d]  = sum_i x[n,i]*Wc[h,i,d] + bc[h,d]
//   ssrc[n,h] = M[n,h,:] . asrc[h]
//   sdst[n,h] = x[n,:] . wdst[h,:] + bdst[h]
// ---------------------------------------------------------------------------
__global__ __launch_bounds__(256) void k_node_transform(
        const float* __restrict__ x, const float* __restrict__ Wc,
        const float* __restrict__ bc, const float* __restrict__ asrc,
        const float* __restrict__ wdst, const float* __restrict__ bdst,
        float* __restrict__ M, float* __restrict__ ssrc, float* __restrict__ sdst) {
    int n = blockIdx.x;
    int t = threadIdx.x;
    int h = t >> 6, d = t & 63;
    __shared__ float xs[DD];
    if (t < DD) xs[t] = x[n * DD + t];
    __syncthreads();
    float acc = bc[h * DD + d];
#pragma unroll 8
    for (int f = 0; f < DD; ++f)
        acc += xs[f] * Wc[h * (DD * DD) + f * DD + d];
    M[(size_t)n * (HH * DD) + h * DD + d] = acc;
    float p = acc * asrc[h * DD + d];
    float q = xs[d] * wdst[h * DD + d];
#pragma unroll
    for (int off = 32; off; off >>= 1) {
        p += __shfl_xor(p, off, 64);
        q += __shfl_xor(q, off, 64);
    }
    if (d == 0) {
        ssrc[n * HH + h] = p;
        sdst[n * HH + h] = q + bdst[h];
    }
}

// ---------------------------------------------------------------------------
// CSR build over a COMBINED segment space of 2N destinations:
//   seg = N + dst  for direction ab (dst in b, output second half)
//   seg =     dst  for direction ba (dst in a, output first half)
// global edge id g = e (ab) or E + e (ba)
// ---------------------------------------------------------------------------
__global__ void k_zero(int* __restrict__ cnt, int* __restrict__ cursor, int n2) {
    int i = blockIdx.x * 256 + threadIdx.x;
    if (i < n2) { cnt[i] = 0; cursor[i] = 0; }
}

__global__ __launch_bounds__(256) void k_count(
        const int* __restrict__ ei_ab, const int* __restrict__ ei_ba,
        int* __restrict__ cnt, int N, int E) {
    int i = blockIdx.x * 256 + threadIdx.x;
    if (i >= 2 * E) return;
    bool ab = i < E;
    int e = ab ? i : i - E;
    int dv = ab ? ei_ab[E + e] : ei_ba[E + e];
    int seg = ab ? N + dv : dv;
    atomicAdd(&cnt[seg], 1);
}

// block-level inclusive scan of 1024 ints (256 thr x 4 items)
__global__ __launch_bounds__(256) void k_scan1(
        const int* __restrict__ cnt, int* __restrict__ tmp,
        int* __restrict__ bsum, int n) {
    int tid = threadIdx.x;
    int base = blockIdx.x * 1024 + tid * 4;
    int v0 = base + 0 < n ? cnt[base + 0] : 0;
    int v1 = base + 1 < n ? cnt[base + 1] : 0;
    int v2 = base + 2 < n ? cnt[base + 2] : 0;
    int v3 = base + 3 < n ? cnt[base + 3] : 0;
    v1 += v0; v2 += v1; v3 += v2;
    int torig = v3;
    int t = torig;
    int lane = tid & 63, wid = tid >> 6;
#pragma unroll
    for (int off = 1; off < 64; off <<= 1) {
        int u = __shfl_up(t, off, 64);
        if (lane >= off) t += u;
    }
    __shared__ int ws[4];
    if (lane == 63) ws[wid] = t;
    __syncthreads();
    int wo = 0;
    for (int w = 0; w < wid; ++w) wo += ws[w];
    int tb = wo + t - torig;   // exclusive offset of this thread
    v0 += tb; v1 += tb; v2 += tb; v3 += tb;
    if (base + 0 < n) tmp[base + 0] = v0;
    if (base + 1 < n) tmp[base + 1] = v1;
    if (base + 2 < n) tmp[base + 2] = v2;
    if (base + 3 < n) tmp[base + 3] = v3;
    if (tid == 0) bsum[blockIdx.x] = ws[0] + ws[1] + ws[2] + ws[3];
}

// single block: bsum[0..nb) -> exclusive prefix sums, in place (nb <= 1024)
__global__ __launch_bounds__(256) void k_scan2(int* __restrict__ bsum, int nb) {
    int tid = threadIdx.x;
    int base = tid * 4;
    int o0 = base + 0 < nb ? bsum[base + 0] : 0;
    int o1 = base + 1 < nb ? bsum[base + 1] : 0;
    int o2 = base + 2 < nb ? bsum[base + 2] : 0;
    int o3 = base + 3 < nb ? bsum[base + 3] : 0;
    int v0 = o0, v1 = o1 + v0, v2 = o2 + v1, v3 = o3 + v2;
    int torig = v3;
    int t = torig;
    int lane = tid & 63, wid = tid >> 6;
#pragma unroll
    for (int off = 1; off < 64; off <<= 1) {
        int u = __shfl_up(t, off, 64);
        if (lane >= off) t += u;
    }
    __shared__ int ws[4];
    if (lane == 63) ws[wid] = t;
    __syncthreads();
    int wo = 0;
    for (int w = 0; w < wid; ++w) wo += ws[w];
    int tb = wo + t - torig;
    v0 += tb; v1 += tb; v2 += tb; v3 += tb;
    if (base + 0 < nb) bsum[base + 0] = v0 - o0;   // exclusive
    if (base + 1 < nb) bsum[base + 1] = v1 - o1;
    if (base + 2 < nb) bsum[base + 2] = v2 - o2;
    if (base + 3 < nb) bsum[base + 3] = v3 - o3;
}

__global__ void k_scan3(const int* __restrict__ tmp, const int* __restrict__ cnt,
                        const int* __restrict__ boff, int* __restrict__ row_start,
                        int n) {
    int i = blockIdx.x * 256 + threadIdx.x;
    if (i < n) row_start[i] = tmp[i] - cnt[i] + boff[i >> 10];
}

__global__ __launch_bounds__(256) void k_fill(
        const int* __restrict__ ei_ab, const int* __restrict__ ei_ba,
        const int* __restrict__ row_start, int* __restrict__ cursor,
        int* __restrict__ edge_list, int N, int E) {
    int i = blockIdx.x * 256 + threadIdx.x;
    if (i >= 2 * E) return;
    bool ab = i < E;
    int e = ab ? i : i - E;
    int dv = ab ? ei_ab[E + e] : ei_ba[E + e];
    int seg = ab ? N + dv : dv;
    int pos = atomicAdd(&cursor[seg], 1);
    edge_list[row_start[seg] + pos] = i;
}

// ---------------------------------------------------------------------------
// Gather: one block per destination segment, wave h = head h, lane = d.
// Exact segment softmax (online across 64-edge chunks) + register-accumulated
// weighted message sum. Each output element written exactly once. ELU fused.
// ---------------------------------------------------------------------------
__global__ __launch_bounds__(256) void k_gather(
        const int* __restrict__ edge_list, const int* __restrict__ row_start,
        const int* __restrict__ cnt,
        const int* __restrict__ ei_ab, const int* __restrict__ et_ab,
        const int* __restrict__ ei_ba, const int* __restrict__ et_ba,
        const float* __restrict__ M_a, const float* __restrict__ M_b,
        const float* __restrict__ mt_ab, const float* __restrict__ mt_ba,
        const float* __restrict__ ssrc_a, const float* __restrict__ ssrc_b,
        const float* __restrict__ sdst_a, const float* __restrict__ sdst_b,
        const float* __restrict__ st_ab, const float* __restrict__ st_ba,
        float* __restrict__ dout, int N, int E) {
    int seg = blockIdx.x;
    int h = threadIdx.x >> 6, lane = threadIdx.x & 63;
    bool isB = seg >= N;               // dst in b  => direction ab, src = a
    int n = isB ? seg - N : seg;
    const int*   ei   = isB ? ei_ab   : ei_ba;
    const int*   et   = isB ? et_ab   : et_ba;
    const float* M    = isB ? M_a     : M_b;
    const float* mt   = isB ? mt_ab   : mt_ba;
    const float* ssrc = isB ? ssrc_a  : ssrc_b;
    const float* sdst = isB ? sdst_b  : sdst_a;
    const float* st   = isB ? st_ab   : st_ba;
    int start = row_start[seg];
    int deg   = cnt[seg];
    float sd = sdst[n * HH + h];
    float m = -INFINITY, den = 0.f, acc = 0.f;
    for (int j0 = 0; j0 < deg; j0 += 64) {
        int j = j0 + lane;
        float l = -INFINITY;
        int s = 0, t = 0;
        if (j < deg) {
            int g = edge_list[start + j];
            int e = isB ? g : (g - E);
            s = ei[e]; t = et[e];
            float l0 = ssrc[s * HH + h] + sd + st[t * HH + h];
            l = l0 > 0.f ? l0 : NEG_SLOPE * l0;
        }
        float cm = l;
#pragma unroll
        for (int off = 32; off; off >>= 1) cm = fmaxf(cm, __shfl_xor(cm, off, 64));
        float nm = fmaxf(m, cm);
        float scale = __expf(m - nm);   // first chunk: exp(-inf)=0, acc/den are 0
        acc *= scale; den *= scale;
        float ex = (j < deg) ? __expf(l - nm) : 0.f;
        float sx = ex;
#pragma unroll
        for (int off = 32; off; off >>= 1) sx += __shfl_xor(sx, off, 64);
        den += sx;
        int cn = (deg - j0) < 64 ? (deg - j0) : 64;
        for (int jj = 0; jj < cn; ++jj) {
            float exj = __shfl(ex, jj, 64);
            int sj = __shfl(s, jj, 64);
            int tj = __shfl(t, jj, 64);
            acc += exj * (M[(size_t)sj * (HH * DD) + h * DD + lane] +
                          mt[tj * (HH * DD) + h * DD + lane]);
        }
        m = nm;
    }
    float v = acc / (den + 1e-16f);
    dout[(size_t)seg * (HH * DD) + h * DD + lane] = v > 0.f ? v : expm1f(v);
}

// ---------------------------------------------------------------------------
extern "C" void kernel_launch(void* const* d_in, const int* in_sizes, int n_in,
                              void* d_out, int out_size, void* d_ws, size_t ws_size,
                              hipStream_t stream) {
    const float* x_a     = (const float*)d_in[0];
    const float* x_b     = (const float*)d_in[1];
    const float* W_a     = (const float*)d_in[2];
    const float* b_a     = (const float*)d_in[3];
    const float* W_b     = (const float*)d_in[4];
    const float* b_b     = (const float*)d_in[5];
    const float* te      = (const float*)d_in[6];
    const float* Wsrc_ab = (const float*)d_in[7];
    const float* Wdst_ab = (const float*)d_in[8];
    const float* asrc_ab = (const float*)d_in[9];
    const float* adst_ab = (const float*)d_in[10];
    const float* Wsrc_ba = (const float*)d_in[11];
    const float* Wdst_ba = (const float*)d_in[12];
    const float* asrc_ba = (const float*)d_in[13];
    const float* adst_ba = (const float*)d_in[14];
    const int*   ei_ab   = (const int*)d_in[15];
    const int*   et_ab   = (const int*)d_in[16];
    const int*   ei_ba   = (const int*)d_in[17];
    const int*   et_ba   = (const int*)d_in[18];
    float* dout = (float*)d_out;

    int N = in_sizes[0] / DD;
    int E = in_sizes[15] / 2;
    int V = in_sizes[6] / DD;
    int N2 = 2 * N;

    // workspace carve-up (256B aligned)
    char* p = (char*)d_ws;
    auto alloc = [&](size_t bytes) {
        char* r = p; p += (bytes + 255) & ~(size_t)255; return r;
    };
    float* M_a      = (float*)alloc((size_t)N * HH * DD * 4);
    float* M_b      = (float*)alloc((size_t)N * HH * DD * 4);
    float* ssrc_a   = (float*)alloc((size_t)N * HH * 4);
    float* sdst_a   = (float*)alloc((size_t)N * HH * 4);
    float* ssrc_b   = (float*)alloc((size_t)N * HH * 4);
    float* sdst_b   = (float*)alloc((size_t)N * HH * 4);
    float* st_ab    = (float*)alloc(V * HH * 4);
    float* st_ba    = (float*)alloc(V * HH * 4);
    float* mt_ab    = (float*)alloc(V * HH * DD * 4);
    float* mt_ba    = (float*)alloc(V * HH * DD * 4);
    float* Wc_a     = (float*)alloc(HH * DD * DD * 4);
    float* Wc_b     = (float*)alloc(HH * DD * DD * 4);
    float* bc_a     = (float*)alloc(HH * DD * 4);
    float* bc_b     = (float*)alloc(HH * DD * 4);
    float* wdst_a   = (float*)alloc(HH * DD * 4);
    float* wdst_b   = (float*)alloc(HH * DD * 4);
    float* bdst_a   = (float*)alloc(HH * 4);
    float* bdst_b   = (float*)alloc(HH * 4);
    float* ub_s_ab  = (float*)alloc(HH * DD * 4);
    float* ub_d_ab  = (float*)alloc(HH * DD * 4);
    float* ut_d_ab  = (float*)alloc(HH * DD * 4);
    float* ub_s_ba  = (float*)alloc(HH * DD * 4);
    float* ub_d_ba  = (float*)alloc(HH * DD * 4);
    float* ut_d_ba  = (float*)alloc(HH * DD * 4);
    int*   cnt      = (int*)alloc((size_t)N2 * 4);
    int*   cursor   = (int*)alloc((size_t)N2 * 4);
    int*   tmp      = (int*)alloc((size_t)N2 * 4);
    int*   row_start= (int*)alloc((size_t)N2 * 4);
    int*   bsum     = (int*)alloc(1024 * 4);
    int*   edge_list= (int*)alloc((size_t)2 * E * 4);

    // 1. fold weights
    k_fold_mats<<<(2 * HH * DD * DD + 255) / 256, 256, 0, stream>>>(
        W_a, Wsrc_ab, W_b, Wsrc_ba, Wc_a, Wc_b);
    k_fold_u<<<3, 256, 0, stream>>>(Wsrc_ab, asrc_ab, Wdst_ab, adst_ab,
                                    ub_s_ab, ub_d_ab, ut_d_ab);
    k_fold_u<<<3, 256, 0, stream>>>(Wsrc_ba, asrc_ba, Wdst_ba, adst_ba,
                                    ub_s_ba, ub_d_ba, ut_d_ba);
    int miscTot = V * HH * DD + HH * DD + V * HH + HH * DD + HH;
    int miscBlocks = (miscTot + 255) / 256;
    k_fold_misc<<<miscBlocks, 256, 0, stream>>>(
        b_a, Wsrc_ab, W_b, b_b, te, V, ub_s_ab, ub_d_ab, ut_d_ab,
        bc_a, st_ab, mt_ab, wdst_b, bdst_b);
    k_fold_misc<<<miscBlocks, 256, 0, stream>>>(
        b_b, Wsrc_ba, W_a, b_a, te, V, ub_s_ba, ub_d_ba, ut_d_ba,
        bc_b, st_ba, mt_ba, wdst_a, bdst_a);

    // 2. node transforms (M, ssrc, sdst)
    k_node_transform<<<N, 256, 0, stream>>>(
        x_a, Wc_a, bc_a, asrc_ab, wdst_a, bdst_a, M_a, ssrc_a, sdst_a);
    k_node_transform<<<N, 256, 0, stream>>>(
        x_b, Wc_b, bc_b, asrc_ba, wdst_b, bdst_b, M_b, ssrc_b, sdst_b);

    // 3. CSR build over combined 2N segment space
    k_zero<<<(N2 + 255) / 256, 256, 0, stream>>>(cnt, cursor, N2);
    k_count<<<(2 * E + 255) / 256, 256, 0, stream>>>(ei_ab, ei_ba, cnt, N, E);
    int nb = (N2 + 1023) / 1024;
    k_scan1<<<nb, 256, 0, stream>>>(cnt, tmp, bsum, N2);
    k_scan2<<<1, 256, 0, stream>>>(bsum, nb);
    k_scan3<<<(N2 + 255) / 256, 256, 0, stream>>>(tmp, cnt, bsum, row_start, N2);
    k_fill<<<(2 * E + 255) / 256, 256, 0, stream>>>(
        ei_ab, ei_ba, row_start, cursor, edge_list, N, E);

    // 4. segment softmax + gather-accumulate + ELU (writes d_out once)
    k_gather<<<N2, 256, 0, stream>>>(
        edge_list, row_start, cnt,
        ei_ab, et_ab, ei_ba, et_ba,
        M_a, M_b, mt_ab, mt_ba,
        ssrc_a, ssrc_b, sdst_a, sdst_b, st_ab, st_ba,
        dout, N, E);
}

// Round 5
// 762.575 us; speedup vs baseline: 3.2288x; 1.4680x over previous
//
#include <hip/hip_runtime.h>
#include <hip/hip_bf16.h>
#include <math.h>

// D=64, H=4 are compile-time; N, E, V read from in_sizes.
#define DD 64
#define HH 4
#define NEG_SLOPE 0.2f

// ---------------------------------------------------------------------------
// Wc[type][h][i][d] = sum_f W[i, h*64+f] * Wsrc[h, f, d]
// ---------------------------------------------------------------------------
__global__ __launch_bounds__(256) void k_fold_mats(
        const float* __restrict__ W_a, const float* __restrict__ Wsrc_ab,
        const float* __restrict__ W_b, const float* __restrict__ Wsrc_ba,
        float* __restrict__ Wc_a, float* __restrict__ Wc_b) {
    int idx = blockIdx.x * 256 + threadIdx.x;   // 0 .. 2*H*64*64-1 = 32767
    int type = idx >> 14;
    int r = idx & 16383;
    int h = r >> 12;
    int i = (r >> 6) & 63;
    int d = r & 63;
    const float* W  = type ? W_b : W_a;
    const float* Ws = type ? Wsrc_ba : Wsrc_ab;
    float* out = type ? Wc_b : Wc_a;
    float acc = 0.f;
#pragma unroll 8
    for (int f = 0; f < DD; ++f)
        acc += W[i * (DD * HH) + h * DD + f] * Ws[h * (2 * DD * DD) + f * DD + d];
    out[r] = acc;
}

// ---------------------------------------------------------------------------
//   ub_s[h,f] = sum_d Wsrc[h, D+f, d] * asrc[h,d]
//   ub_d[h,f] = sum_d Wdst[h, D+f, d] * adst[h,d]
//   ut_d[h,f] = sum_d Wdst[h, f,   d] * adst[h,d]
// ---------------------------------------------------------------------------
__global__ __launch_bounds__(256) void k_fold_u(
        const float* __restrict__ Wsrc, const float* __restrict__ asrc,
        const float* __restrict__ Wdst, const float* __restrict__ adst,
        float* __restrict__ ub_s, float* __restrict__ ub_d, float* __restrict__ ut_d) {
    int idx = blockIdx.x * 256 + threadIdx.x;  // 0 .. 3*H*D-1 = 767
    if (idx >= 3 * HH * DD) return;
    const int S2 = 2 * DD * DD;
    int kind = idx >> 8;
    int r = idx & 255;
    int h = r >> 6, f = r & 63;
    const float* Wm = (kind == 0) ? Wsrc : Wdst;
    const float* av = (kind == 0) ? asrc : adst;
    int row = (kind == 2) ? f : (DD + f);
    float acc = 0.f;
#pragma unroll 8
    for (int d = 0; d < DD; ++d)
        acc += Wm[h * S2 + row * DD + d] * av[h * DD + d];
    float* out = (kind == 0) ? ub_s : (kind == 1) ? ub_d : ut_d;
    out[r] = acc;
}

// ---------------------------------------------------------------------------
// Per-direction small folds — every output is a single 64-MAC loop.
// ---------------------------------------------------------------------------
__global__ __launch_bounds__(256) void k_fold_misc(
        const float* __restrict__ b_src, const float* __restrict__ Wsrc,
        const float* __restrict__ W_dst, const float* __restrict__ b_dst,
        const float* __restrict__ te, int V,
        const float* __restrict__ ub_s, const float* __restrict__ ub_d,
        const float* __restrict__ ut_d,
        float* __restrict__ bc, float* __restrict__ st, float* __restrict__ mt,
        float* __restrict__ wdst, float* __restrict__ bdst) {
    int idx = blockIdx.x * 256 + threadIdx.x;
    const int S2 = 2 * DD * DD;
    int mtN = V * HH * DD;
    if (idx < mtN) {                     // mt[t*256 + h*64 + d]
        int t = idx >> 8, h = (idx >> 6) & 3, d = idx & 63;
        float acc = 0.f;
#pragma unroll 8
        for (int f = 0; f < DD; ++f)
            acc += te[t * DD + f] * Wsrc[h * S2 + (DD + f) * DD + d];
        mt[idx] = acc;
        return;
    }
    idx -= mtN;
    if (idx < HH * DD) {                 // bc[h*64+d]
        int h = idx >> 6, d = idx & 63;
        float acc = 0.f;
#pragma unroll 8
        for (int f = 0; f < DD; ++f)
            acc += b_src[h * DD + f] * Wsrc[h * S2 + f * DD + d];
        bc[idx] = acc;
        return;
    }
    idx -= HH * DD;
    if (idx < V * HH) {                  // st[t*4+h]
        int t = idx >> 2, h = idx & 3;
        float acc = 0.f;
#pragma unroll 8
        for (int f = 0; f < DD; ++f)
            acc += te[t * DD + f] * (ub_s[h * DD + f] + ub_d[h * DD + f]);
        st[idx] = acc;
        return;
    }
    idx -= V * HH;
    if (idx < HH * DD) {                 // wdst[h*64+i]
        int h = idx >> 6, i = idx & 63;
        float acc = 0.f;
#pragma unroll 8
        for (int f = 0; f < DD; ++f)
            acc += W_dst[i * (DD * HH) + h * DD + f] * ut_d[h * DD + f];
        wdst[idx] = acc;
        return;
    }
    idx -= HH * DD;
    if (idx < HH) {                      // bdst[h]
        int h = idx;
        float acc = 0.f;
#pragma unroll 8
        for (int f = 0; f < DD; ++f)
            acc += b_dst[h * DD + f] * ut_d[h * DD + f];
        bdst[h] = acc;
    }
}

// ---------------------------------------------------------------------------
// Node transform, Wc stationary in registers.
// Block = 4 waves; wave w = head w; block covers 64 nodes. lane = d.
//   wc_v[f] = Wc[h][f][lane]  (64 VGPRs, loaded once per block)
//   x row read via wave-uniform loads (scalar pipe); M store coalesced.
//   M[n,h,d] = sum_f x[n,f]*wc_v[f] + bc; ssrc = M.asrc; sdst = x.wdst + bdst
// ---------------------------------------------------------------------------
__global__ __launch_bounds__(256) void k_node_transform(
        const float* __restrict__ x, const float* __restrict__ Wc,
        const float* __restrict__ bc, const float* __restrict__ asrc,
        const float* __restrict__ wdst, const float* __restrict__ bdst,
        float* __restrict__ M, float* __restrict__ ssrc, float* __restrict__ sdst,
        int N) {
    int h = threadIdx.x >> 6, lane = threadIdx.x & 63;
    int n0 = blockIdx.x * 64;
    float wc_v[DD];
#pragma unroll
    for (int f = 0; f < DD; ++f)
        wc_v[f] = Wc[h * (DD * DD) + f * DD + lane];
    float asrc_v = asrc[h * DD + lane];
    float wdst_v = wdst[h * DD + lane];
    float bc_v   = bc[h * DD + lane];
    float bdst_s = bdst[h];
    int nEnd = N - n0 < 64 ? N - n0 : 64;
    for (int n = 0; n < nEnd; ++n) {
        const float* xrow = x + (size_t)(n0 + n) * DD;   // uniform -> s_load
        float acc = bc_v;
#pragma unroll
        for (int f4 = 0; f4 < DD / 4; ++f4) {
            float4 xq = *reinterpret_cast<const float4*>(xrow + f4 * 4);
            acc = fmaf(xq.x, wc_v[f4 * 4 + 0], acc);
            acc = fmaf(xq.y, wc_v[f4 * 4 + 1], acc);
            acc = fmaf(xq.z, wc_v[f4 * 4 + 2], acc);
            acc = fmaf(xq.w, wc_v[f4 * 4 + 3], acc);
        }
        M[(size_t)(n0 + n) * (HH * DD) + h * DD + lane] = acc;
        float p = acc * asrc_v;
        float q = xrow[lane] * wdst_v;       // per-lane coalesced load
#pragma unroll
        for (int off = 32; off; off >>= 1) {
            p += __shfl_xor(p, off, 64);
            q += __shfl_xor(q, off, 64);
        }
        if (lane == 0) {
            ssrc[(n0 + n) * HH + h] = p;
            sdst[(n0 + n) * HH + h] = q + bdst_s;
        }
    }
}

// ---------------------------------------------------------------------------
// CSR build over a COMBINED segment space of 2N destinations:
//   seg = N + dst  for direction ab (dst in b, output second half)
//   seg =     dst  for direction ba (dst in a, output first half)
// edge_list records are (src, type) int2 — no per-edge gathers later.
// ---------------------------------------------------------------------------
__global__ void k_zero(int* __restrict__ cnt, int* __restrict__ cursor, int n2) {
    int i = blockIdx.x * 256 + threadIdx.x;
    if (i < n2) { cnt[i] = 0; cursor[i] = 0; }
}

__global__ __launch_bounds__(256) void k_count(
        const int* __restrict__ ei_ab, const int* __restrict__ ei_ba,
        int* __restrict__ cnt, int N, int E) {
    int i = blockIdx.x * 256 + threadIdx.x;
    if (i >= 2 * E) return;
    bool ab = i < E;
    int e = ab ? i : i - E;
    int dv = ab ? ei_ab[E + e] : ei_ba[E + e];
    int seg = ab ? N + dv : dv;
    atomicAdd(&cnt[seg], 1);
}

// block-level inclusive scan of 1024 ints (256 thr x 4 items)
__global__ __launch_bounds__(256) void k_scan1(
        const int* __restrict__ cnt, int* __restrict__ tmp,
        int* __restrict__ bsum, int n) {
    int tid = threadIdx.x;
    int base = blockIdx.x * 1024 + tid * 4;
    int v0 = base + 0 < n ? cnt[base + 0] : 0;
    int v1 = base + 1 < n ? cnt[base + 1] : 0;
    int v2 = base + 2 < n ? cnt[base + 2] : 0;
    int v3 = base + 3 < n ? cnt[base + 3] : 0;
    v1 += v0; v2 += v1; v3 += v2;
    int torig = v3;
    int t = torig;
    int lane = tid & 63, wid = tid >> 6;
#pragma unroll
    for (int off = 1; off < 64; off <<= 1) {
        int u = __shfl_up(t, off, 64);
        if (lane >= off) t += u;
    }
    __shared__ int ws[4];
    if (lane == 63) ws[wid] = t;
    __syncthreads();
    int wo = 0;
    for (int w = 0; w < wid; ++w) wo += ws[w];
    int tb = wo + t - torig;   // exclusive offset of this thread
    v0 += tb; v1 += tb; v2 += tb; v3 += tb;
    if (base + 0 < n) tmp[base + 0] = v0;
    if (base + 1 < n) tmp[base + 1] = v1;
    if (base + 2 < n) tmp[base + 2] = v2;
    if (base + 3 < n) tmp[base + 3] = v3;
    if (tid == 0) bsum[blockIdx.x] = ws[0] + ws[1] + ws[2] + ws[3];
}

// single block: bsum[0..nb) -> exclusive prefix sums, in place (nb <= 1024)
__global__ __launch_bounds__(256) void k_scan2(int* __restrict__ bsum, int nb) {
    int tid = threadIdx.x;
    int base = tid * 4;
    int o0 = base + 0 < nb ? bsum[base + 0] : 0;
    int o1 = base + 1 < nb ? bsum[base + 1] : 0;
    int o2 = base + 2 < nb ? bsum[base + 2] : 0;
    int o3 = base + 3 < nb ? bsum[base + 3] : 0;
    int v0 = o0, v1 = o1 + v0, v2 = o2 + v1, v3 = o3 + v2;
    int torig = v3;
    int t = torig;
    int lane = tid & 63, wid = tid >> 6;
#pragma unroll
    for (int off = 1; off < 64; off <<= 1) {
        int u = __shfl_up(t, off, 64);
        if (lane >= off) t += u;
    }
    __shared__ int ws[4];
    if (lane == 63) ws[wid] = t;
    __syncthreads();
    int wo = 0;
    for (int w = 0; w < wid; ++w) wo += ws[w];
    int tb = wo + t - torig;
    v0 += tb; v1 += tb; v2 += tb; v3 += tb;
    if (base + 0 < nb) bsum[base + 0] = v0 - o0;   // exclusive
    if (base + 1 < nb) bsum[base + 1] = v1 - o1;
    if (base + 2 < nb) bsum[base + 2] = v2 - o2;
    if (base + 3 < nb) bsum[base + 3] = v3 - o3;
}

__global__ void k_scan3(const int* __restrict__ tmp, const int* __restrict__ cnt,
                        const int* __restrict__ boff, int* __restrict__ row_start,
                        int n) {
    int i = blockIdx.x * 256 + threadIdx.x;
    if (i < n) row_start[i] = tmp[i] - cnt[i] + boff[i >> 10];
}

__global__ __launch_bounds__(256) void k_fill(
        const int* __restrict__ ei_ab, const int* __restrict__ et_ab,
        const int* __restrict__ ei_ba, const int* __restrict__ et_ba,
        const int* __restrict__ row_start, int* __restrict__ cursor,
        int2* __restrict__ edge_list, int N, int E) {
    int i = blockIdx.x * 256 + threadIdx.x;
    if (i >= 2 * E) return;
    bool ab = i < E;
    int e = ab ? i : i - E;
    int s  = ab ? ei_ab[e]     : ei_ba[e];
    int dv = ab ? ei_ab[E + e] : ei_ba[E + e];
    int t  = ab ? et_ab[e]     : et_ba[e];
    int seg = ab ? N + dv : dv;
    int pos = atomicAdd(&cursor[seg], 1);
    edge_list[row_start[seg] + pos] = make_int2(s, t);
}

// ---------------------------------------------------------------------------
// Gather: ONE WAVE per destination segment (avg degree ~2).
// lane = (h, q): h = lane>>4 (head), q = lane&15 (float4 quarter of d).
// One dwordx4 per lane fetches the whole 1KB M row coalesced.
// Flash-style single-pass online softmax, fully per-lane (no shuffles).
// Output written once, coalesced, ELU fused.
// ---------------------------------------------------------------------------
__global__ __launch_bounds__(256) void k_gather(
        const int2* __restrict__ edge_list, const int* __restrict__ row_start,
        const int* __restrict__ cnt,
        const float* __restrict__ M_a, const float* __restrict__ M_b,
        const float* __restrict__ mt_ab, const float* __restrict__ mt_ba,
        const float* __restrict__ ssrc_a, const float* __restrict__ ssrc_b,
        const float* __restrict__ sdst_a, const float* __restrict__ sdst_b,
        const float* __restrict__ st_ab, const float* __restrict__ st_ba,
        float* __restrict__ dout, int N) {
    int wid = (blockIdx.x * 256 + threadIdx.x) >> 6;   // wave id = segment
    if (wid >= 2 * N) return;
    int seg = wid;
    int lane = threadIdx.x & 63;
    int h = lane >> 4;
    bool isB = seg >= N;               // dst in b => direction ab, src = a
    int n = isB ? seg - N : seg;
    const float* M    = isB ? M_a    : M_b;
    const float* mt   = isB ? mt_ab  : mt_ba;
    const float* ssrc = isB ? ssrc_a : ssrc_b;
    const float* sdst = isB ? sdst_b : sdst_a;
    const float* st   = isB ? st_ab  : st_ba;
    int start = row_start[seg];
    int deg   = cnt[seg];
    float sd = sdst[n * HH + h];
    float m = -INFINITY, den = 0.f;
    float ax = 0.f, ay = 0.f, az = 0.f, aw = 0.f;
    for (int j = 0; j < deg; ++j) {
        int2 rec = edge_list[start + j];       // uniform -> scalar load
        int s = rec.x, t = rec.y;
        float l0 = ssrc[s * HH + h] + sd + st[t * HH + h];
        float l = l0 > 0.f ? l0 : NEG_SLOPE * l0;
        float nm = fmaxf(m, l);
        float sc = __expf(m - nm);             // first iter: exp(-inf)=0
        float w  = __expf(l - nm);
        den = den * sc + w;
        float4 Mv = *reinterpret_cast<const float4*>(M  + (size_t)s * (HH * DD) + lane * 4);
        float4 Tv = *reinterpret_cast<const float4*>(mt + (size_t)t * (HH * DD) + lane * 4);
        ax = ax * sc + w * (Mv.x + Tv.x);
        ay = ay * sc + w * (Mv.y + Tv.y);
        az = az * sc + w * (Mv.z + Tv.z);
        aw = aw * sc + w * (Mv.w + Tv.w);
        m = nm;
    }
    float inv = 1.f / (den + 1e-16f);
    float4 v;
    v.x = ax * inv; v.x = v.x > 0.f ? v.x : expm1f(v.x);
    v.y = ay * inv; v.y = v.y > 0.f ? v.y : expm1f(v.y);
    v.z = az * inv; v.z = v.z > 0.f ? v.z : expm1f(v.z);
    v.w = aw * inv; v.w = v.w > 0.f ? v.w : expm1f(v.w);
    *reinterpret_cast<float4*>(dout + (size_t)seg * (HH * DD) + lane * 4) = v;
}

// ---------------------------------------------------------------------------
extern "C" void kernel_launch(void* const* d_in, const int* in_sizes, int n_in,
                              void* d_out, int out_size, void* d_ws, size_t ws_size,
                              hipStream_t stream) {
    const float* x_a     = (const float*)d_in[0];
    const float* x_b     = (const float*)d_in[1];
    const float* W_a     = (const float*)d_in[2];
    const float* b_a     = (const float*)d_in[3];
    const float* W_b     = (const float*)d_in[4];
    const float* b_b     = (const float*)d_in[5];
    const float* te      = (const float*)d_in[6];
    const float* Wsrc_ab = (const float*)d_in[7];
    const float* Wdst_ab = (const float*)d_in[8];
    const float* asrc_ab = (const float*)d_in[9];
    const float* adst_ab = (const float*)d_in[10];
    const float* Wsrc_ba = (const float*)d_in[11];
    const float* Wdst_ba = (const float*)d_in[12];
    const float* asrc_ba = (const float*)d_in[13];
    const float* adst_ba = (const float*)d_in[14];
    const int*   ei_ab   = (const int*)d_in[15];
    const int*   et_ab   = (const int*)d_in[16];
    const int*   ei_ba   = (const int*)d_in[17];
    const int*   et_ba   = (const int*)d_in[18];
    float* dout = (float*)d_out;

    int N = in_sizes[0] / DD;
    int E = in_sizes[15] / 2;
    int V = in_sizes[6] / DD;
    int N2 = 2 * N;

    // workspace carve-up (256B aligned)
    char* p = (char*)d_ws;
    auto alloc = [&](size_t bytes) {
        char* r = p; p += (bytes + 255) & ~(size_t)255; return r;
    };
    float* M_a      = (float*)alloc((size_t)N * HH * DD * 4);
    float* M_b      = (float*)alloc((size_t)N * HH * DD * 4);
    float* ssrc_a   = (float*)alloc((size_t)N * HH * 4);
    float* sdst_a   = (float*)alloc((size_t)N * HH * 4);
    float* ssrc_b   = (float*)alloc((size_t)N * HH * 4);
    float* sdst_b   = (float*)alloc((size_t)N * HH * 4);
    float* st_ab    = (float*)alloc(V * HH * 4);
    float* st_ba    = (float*)alloc(V * HH * 4);
    float* mt_ab    = (float*)alloc(V * HH * DD * 4);
    float* mt_ba    = (float*)alloc(V * HH * DD * 4);
    float* Wc_a     = (float*)alloc(HH * DD * DD * 4);
    float* Wc_b     = (float*)alloc(HH * DD * DD * 4);
    float* bc_a     = (float*)alloc(HH * DD * 4);
    float* bc_b     = (float*)alloc(HH * DD * 4);
    float* wdst_a   = (float*)alloc(HH * DD * 4);
    float* wdst_b   = (float*)alloc(HH * DD * 4);
    float* bdst_a   = (float*)alloc(HH * 4);
    float* bdst_b   = (float*)alloc(HH * 4);
    float* ub_s_ab  = (float*)alloc(HH * DD * 4);
    float* ub_d_ab  = (float*)alloc(HH * DD * 4);
    float* ut_d_ab  = (float*)alloc(HH * DD * 4);
    float* ub_s_ba  = (float*)alloc(HH * DD * 4);
    float* ub_d_ba  = (float*)alloc(HH * DD * 4);
    float* ut_d_ba  = (float*)alloc(HH * DD * 4);
    int*   cnt      = (int*)alloc((size_t)N2 * 4);
    int*   cursor   = (int*)alloc((size_t)N2 * 4);
    int*   tmp      = (int*)alloc((size_t)N2 * 4);
    int*   row_start= (int*)alloc((size_t)N2 * 4);
    int*   bsum     = (int*)alloc(1024 * 4);
    int2*  edge_list= (int2*)alloc((size_t)2 * E * 8);

    // 1. fold weights
    k_fold_mats<<<(2 * HH * DD * DD + 255) / 256, 256, 0, stream>>>(
        W_a, Wsrc_ab, W_b, Wsrc_ba, Wc_a, Wc_b);
    k_fold_u<<<3, 256, 0, stream>>>(Wsrc_ab, asrc_ab, Wdst_ab, adst_ab,
                                    ub_s_ab, ub_d_ab, ut_d_ab);
    k_fold_u<<<3, 256, 0, stream>>>(Wsrc_ba, asrc_ba, Wdst_ba, adst_ba,
                                    ub_s_ba, ub_d_ba, ut_d_ba);
    int miscTot = V * HH * DD + HH * DD + V * HH + HH * DD + HH;
    int miscBlocks = (miscTot + 255) / 256;
    k_fold_misc<<<miscBlocks, 256, 0, stream>>>(
        b_a, Wsrc_ab, W_b, b_b, te, V, ub_s_ab, ub_d_ab, ut_d_ab,
        bc_a, st_ab, mt_ab, wdst_b, bdst_b);
    k_fold_misc<<<miscBlocks, 256, 0, stream>>>(
        b_b, Wsrc_ba, W_a, b_a, te, V, ub_s_ba, ub_d_ba, ut_d_ba,
        bc_b, st_ba, mt_ba, wdst_a, bdst_a);

    // 2. node transforms (M, ssrc, sdst) — Wc in registers
    int ntBlocks = (N + 63) / 64;
    k_node_transform<<<ntBlocks, 256, 0, stream>>>(
        x_a, Wc_a, bc_a, asrc_ab, wdst_a, bdst_a, M_a, ssrc_a, sdst_a, N);
    k_node_transform<<<ntBlocks, 256, 0, stream>>>(
        x_b, Wc_b, bc_b, asrc_ba, wdst_b, bdst_b, M_b, ssrc_b, sdst_b, N);

    // 3. CSR build over combined 2N segment space
    k_zero<<<(N2 + 255) / 256, 256, 0, stream>>>(cnt, cursor, N2);
    k_count<<<(2 * E + 255) / 256, 256, 0, stream>>>(ei_ab, ei_ba, cnt, N, E);
    int nb = (N2 + 1023) / 1024;
    k_scan1<<<nb, 256, 0, stream>>>(cnt, tmp, bsum, N2);
    k_scan2<<<1, 256, 0, stream>>>(bsum, nb);
    k_scan3<<<(N2 + 255) / 256, 256, 0, stream>>>(tmp, cnt, bsum, row_start, N2);
    k_fill<<<(2 * E + 255) / 256, 256, 0, stream>>>(
        ei_ab, et_ab, ei_ba, et_ba, row_start, cursor, edge_list, N, E);

    // 4. one wave per segment: online softmax + gather + ELU
    k_gather<<<(N2 + 3) / 4, 256, 0, stream>>>(
        edge_list, row_start, cnt,
        M_a, M_b, mt_ab, mt_ba,
        ssrc_a, ssrc_b, sdst_a, sdst_b, st_ab, st_ba,
        dout, N);
}

// Round 6
// 724.647 us; speedup vs baseline: 3.3978x; 1.0523x over previous
//
#include <hip/hip_runtime.h>
#include <hip/hip_bf16.h>
#include <math.h>

// D=64, H=4 are compile-time; N, E, V read from in_sizes.
#define DD 64
#define HH 4
#define NEG_SLOPE 0.2f

// ---------------------------------------------------------------------------
// Wc[type][h][i][d] = sum_f W[i, h*64+f] * Wsrc[h, f, d]
// ---------------------------------------------------------------------------
__global__ __launch_bounds__(256) void k_fold_mats(
        const float* __restrict__ W_a, const float* __restrict__ Wsrc_ab,
        const float* __restrict__ W_b, const float* __restrict__ Wsrc_ba,
        float* __restrict__ Wc_a, float* __restrict__ Wc_b) {
    int idx = blockIdx.x * 256 + threadIdx.x;   // 0 .. 2*H*64*64-1 = 32767
    int type = idx >> 14;
    int r = idx & 16383;
    int h = r >> 12;
    int i = (r >> 6) & 63;
    int d = r & 63;
    const float* W  = type ? W_b : W_a;
    const float* Ws = type ? Wsrc_ba : Wsrc_ab;
    float* out = type ? Wc_b : Wc_a;
    float acc = 0.f;
#pragma unroll 8
    for (int f = 0; f < DD; ++f)
        acc += W[i * (DD * HH) + h * DD + f] * Ws[h * (2 * DD * DD) + f * DD + d];
    out[r] = acc;
}

// ---------------------------------------------------------------------------
//   ub_s[h,f] = sum_d Wsrc[h, D+f, d] * asrc[h,d]
//   ub_d[h,f] = sum_d Wdst[h, D+f, d] * adst[h,d]
//   ut_d[h,f] = sum_d Wdst[h, f,   d] * adst[h,d]
// ---------------------------------------------------------------------------
__global__ __launch_bounds__(256) void k_fold_u(
        const float* __restrict__ Wsrc, const float* __restrict__ asrc,
        const float* __restrict__ Wdst, const float* __restrict__ adst,
        float* __restrict__ ub_s, float* __restrict__ ub_d, float* __restrict__ ut_d) {
    int idx = blockIdx.x * 256 + threadIdx.x;  // 0 .. 3*H*D-1 = 767
    if (idx >= 3 * HH * DD) return;
    const int S2 = 2 * DD * DD;
    int kind = idx >> 8;
    int r = idx & 255;
    int h = r >> 6, f = r & 63;
    const float* Wm = (kind == 0) ? Wsrc : Wdst;
    const float* av = (kind == 0) ? asrc : adst;
    int row = (kind == 2) ? f : (DD + f);
    float acc = 0.f;
#pragma unroll 8
    for (int d = 0; d < DD; ++d)
        acc += Wm[h * S2 + row * DD + d] * av[h * DD + d];
    float* out = (kind == 0) ? ub_s : (kind == 1) ? ub_d : ut_d;
    out[r] = acc;
}

// ---------------------------------------------------------------------------
// Per-direction small folds — every output is a single 64-MAC loop.
// ---------------------------------------------------------------------------
__global__ __launch_bounds__(256) void k_fold_misc(
        const float* __restrict__ b_src, const float* __restrict__ Wsrc,
        const float* __restrict__ W_dst, const float* __restrict__ b_dst,
        const float* __restrict__ te, int V,
        const float* __restrict__ ub_s, const float* __restrict__ ub_d,
        const float* __restrict__ ut_d,
        float* __restrict__ bc, float* __restrict__ st, float* __restrict__ mt,
        float* __restrict__ wdst, float* __restrict__ bdst) {
    int idx = blockIdx.x * 256 + threadIdx.x;
    const int S2 = 2 * DD * DD;
    int mtN = V * HH * DD;
    if (idx < mtN) {                     // mt[t*256 + h*64 + d]
        int t = idx >> 8, h = (idx >> 6) & 3, d = idx & 63;
        float acc = 0.f;
#pragma unroll 8
        for (int f = 0; f < DD; ++f)
            acc += te[t * DD + f] * Wsrc[h * S2 + (DD + f) * DD + d];
        mt[idx] = acc;
        return;
    }
    idx -= mtN;
    if (idx < HH * DD) {                 // bc[h*64+d]
        int h = idx >> 6, d = idx & 63;
        float acc = 0.f;
#pragma unroll 8
        for (int f = 0; f < DD; ++f)
            acc += b_src[h * DD + f] * Wsrc[h * S2 + f * DD + d];
        bc[idx] = acc;
        return;
    }
    idx -= HH * DD;
    if (idx < V * HH) {                  // st[t*4+h]
        int t = idx >> 2, h = idx & 3;
        float acc = 0.f;
#pragma unroll 8
        for (int f = 0; f < DD; ++f)
            acc += te[t * DD + f] * (ub_s[h * DD + f] + ub_d[h * DD + f]);
        st[idx] = acc;
        return;
    }
    idx -= V * HH;
    if (idx < HH * DD) {                 // wdst[h*64+i]
        int h = idx >> 6, i = idx & 63;
        float acc = 0.f;
#pragma unroll 8
        for (int f = 0; f < DD; ++f)
            acc += W_dst[i * (DD * HH) + h * DD + f] * ut_d[h * DD + f];
        wdst[idx] = acc;
        return;
    }
    idx -= HH * DD;
    if (idx < HH) {                      // bdst[h]
        int h = idx;
        float acc = 0.f;
#pragma unroll 8
        for (int f = 0; f < DD; ++f)
            acc += b_dst[h * DD + f] * ut_d[h * DD + f];
        bdst[h] = acc;
    }
}

// ---------------------------------------------------------------------------
// Node transform with 8-node ILP.
// Block = 4 waves; wave h = head h; block covers 64 nodes in groups of 8.
// lane = d. Per f4-step: 4 per-lane Wc loads (amortized over 8 nodes) +
// 8 wave-uniform x float4 loads (scalar pipe) + 32 independent FMAs.
// 8 independent accumulator chains hide FMA latency (4cyc lat / 2cyc tput).
//   M[n,h,d] = sum_f x[n,f]*Wc[h,f,d] + bc
//   ssrc[n,h] = M[n,h,:].asrc[h];  sdst[n,h] = x[n,:].wdst[h,:] + bdst[h]
// ---------------------------------------------------------------------------
__global__ __launch_bounds__(256) void k_node_transform(
        const float* __restrict__ x, const float* __restrict__ Wc,
        const float* __restrict__ bc, const float* __restrict__ asrc,
        const float* __restrict__ wdst, const float* __restrict__ bdst,
        float* __restrict__ M, float* __restrict__ ssrc, float* __restrict__ sdst,
        int N) {
    int h = threadIdx.x >> 6, lane = threadIdx.x & 63;
    int n0 = blockIdx.x * 64;
    const float* WcH = Wc + h * (DD * DD);
    float asrc_v = asrc[h * DD + lane];
    float wdst_v = wdst[h * DD + lane];
    float bc_v   = bc[h * DD + lane];
    float bdst_s = bdst[h];
    int nEnd = (N - n0 < 64) ? (N - n0) : 64;
    for (int g = 0; g < nEnd; g += 8) {
        // safe (clamped) row pointers; results for nj>=N are discarded
        const float* xr[8];
#pragma unroll
        for (int j = 0; j < 8; ++j) {
            int nj = n0 + g + j;
            if (nj > N - 1) nj = N - 1;
            xr[j] = x + (size_t)nj * DD;
        }
        float acc[8];
#pragma unroll
        for (int j = 0; j < 8; ++j) acc[j] = bc_v;
#pragma unroll
        for (int f4 = 0; f4 < DD / 4; ++f4) {
            float w0 = WcH[(f4 * 4 + 0) * DD + lane];
            float w1 = WcH[(f4 * 4 + 1) * DD + lane];
            float w2 = WcH[(f4 * 4 + 2) * DD + lane];
            float w3 = WcH[(f4 * 4 + 3) * DD + lane];
#pragma unroll
            for (int j = 0; j < 8; ++j) {
                float4 xq = *reinterpret_cast<const float4*>(xr[j] + f4 * 4);
                float t = fmaf(xq.x, w0, acc[j]);
                t = fmaf(xq.y, w1, t);
                t = fmaf(xq.z, w2, t);
                acc[j] = fmaf(xq.w, w3, t);
            }
        }
        // stores + attention scalars
        float p[8], q[8];
#pragma unroll
        for (int j = 0; j < 8; ++j) {
            int nj = n0 + g + j;
            if (nj < N)
                M[(size_t)nj * (HH * DD) + h * DD + lane] = acc[j];
            p[j] = acc[j] * asrc_v;
            q[j] = xr[j][lane] * wdst_v;   // per-lane coalesced load
        }
        // 16 independent butterflies — pipelined DS ops
#pragma unroll
        for (int off = 32; off; off >>= 1) {
#pragma unroll
            for (int j = 0; j < 8; ++j) {
                p[j] += __shfl_xor(p[j], off, 64);
                q[j] += __shfl_xor(q[j], off, 64);
            }
        }
        if (lane == 0) {
#pragma unroll
            for (int j = 0; j < 8; ++j) {
                int nj = n0 + g + j;
                if (nj < N) {
                    ssrc[nj * HH + h] = p[j];
                    sdst[nj * HH + h] = q[j] + bdst_s;
                }
            }
        }
    }
}

// ---------------------------------------------------------------------------
// CSR build over a COMBINED segment space of 2N destinations:
//   seg = N + dst  for direction ab (dst in b, output second half)
//   seg =     dst  for direction ba (dst in a, output first half)
// edge_list records are (src, type) int2 — no per-edge gathers later.
// ---------------------------------------------------------------------------
__global__ void k_zero(int* __restrict__ cnt, int* __restrict__ cursor, int n2) {
    int i = blockIdx.x * 256 + threadIdx.x;
    if (i < n2) { cnt[i] = 0; cursor[i] = 0; }
}

__global__ __launch_bounds__(256) void k_count(
        const int* __restrict__ ei_ab, const int* __restrict__ ei_ba,
        int* __restrict__ cnt, int N, int E) {
    int i = blockIdx.x * 256 + threadIdx.x;
    if (i >= 2 * E) return;
    bool ab = i < E;
    int e = ab ? i : i - E;
    int dv = ab ? ei_ab[E + e] : ei_ba[E + e];
    int seg = ab ? N + dv : dv;
    atomicAdd(&cnt[seg], 1);
}

// block-level inclusive scan of 1024 ints (256 thr x 4 items)
__global__ __launch_bounds__(256) void k_scan1(
        const int* __restrict__ cnt, int* __restrict__ tmp,
        int* __restrict__ bsum, int n) {
    int tid = threadIdx.x;
    int base = blockIdx.x * 1024 + tid * 4;
    int v0 = base + 0 < n ? cnt[base + 0] : 0;
    int v1 = base + 1 < n ? cnt[base + 1] : 0;
    int v2 = base + 2 < n ? cnt[base + 2] : 0;
    int v3 = base + 3 < n ? cnt[base + 3] : 0;
    v1 += v0; v2 += v1; v3 += v2;
    int torig = v3;
    int t = torig;
    int lane = tid & 63, wid = tid >> 6;
#pragma unroll
    for (int off = 1; off < 64; off <<= 1) {
        int u = __shfl_up(t, off, 64);
        if (lane >= off) t += u;
    }
    __shared__ int ws[4];
    if (lane == 63) ws[wid] = t;
    __syncthreads();
    int wo = 0;
    for (int w = 0; w < wid; ++w) wo += ws[w];
    int tb = wo + t - torig;   // exclusive offset of this thread
    v0 += tb; v1 += tb; v2 += tb; v3 += tb;
    if (base + 0 < n) tmp[base + 0] = v0;
    if (base + 1 < n) tmp[base + 1] = v1;
    if (base + 2 < n) tmp[base + 2] = v2;
    if (base + 3 < n) tmp[base + 3] = v3;
    if (tid == 0) bsum[blockIdx.x] = ws[0] + ws[1] + ws[2] + ws[3];
}

// single block: bsum[0..nb) -> exclusive prefix sums, in place (nb <= 1024)
__global__ __launch_bounds__(256) void k_scan2(int* __restrict__ bsum, int nb) {
    int tid = threadIdx.x;
    int base = tid * 4;
    int o0 = base + 0 < nb ? bsum[base + 0] : 0;
    int o1 = base + 1 < nb ? bsum[base + 1] : 0;
    int o2 = base + 2 < nb ? bsum[base + 2] : 0;
    int o3 = base + 3 < nb ? bsum[base + 3] : 0;
    int v0 = o0, v1 = o1 + v0, v2 = o2 + v1, v3 = o3 + v2;
    int torig = v3;
    int t = torig;
    int lane = tid & 63, wid = tid >> 6;
#pragma unroll
    for (int off = 1; off < 64; off <<= 1) {
        int u = __shfl_up(t, off, 64);
        if (lane >= off) t += u;
    }
    __shared__ int ws[4];
    if (lane == 63) ws[wid] = t;
    __syncthreads();
    int wo = 0;
    for (int w = 0; w < wid; ++w) wo += ws[w];
    int tb = wo + t - torig;
    v0 += tb; v1 += tb; v2 += tb; v3 += tb;
    if (base + 0 < nb) bsum[base + 0] = v0 - o0;   // exclusive
    if (base + 1 < nb) bsum[base + 1] = v1 - o1;
    if (base + 2 < nb) bsum[base + 2] = v2 - o2;
    if (base + 3 < nb) bsum[base + 3] = v3 - o3;
}

__global__ void k_scan3(const int* __restrict__ tmp, const int* __restrict__ cnt,
                        const int* __restrict__ boff, int* __restrict__ row_start,
                        int n) {
    int i = blockIdx.x * 256 + threadIdx.x;
    if (i < n) row_start[i] = tmp[i] - cnt[i] + boff[i >> 10];
}

__global__ __launch_bounds__(256) void k_fill(
        const int* __restrict__ ei_ab, const int* __restrict__ et_ab,
        const int* __restrict__ ei_ba, const int* __restrict__ et_ba,
        const int* __restrict__ row_start, int* __restrict__ cursor,
        int2* __restrict__ edge_list, int N, int E) {
    int i = blockIdx.x * 256 + threadIdx.x;
    if (i >= 2 * E) return;
    bool ab = i < E;
    int e = ab ? i : i - E;
    int s  = ab ? ei_ab[e]     : ei_ba[e];
    int dv = ab ? ei_ab[E + e] : ei_ba[E + e];
    int t  = ab ? et_ab[e]     : et_ba[e];
    int seg = ab ? N + dv : dv;
    int pos = atomicAdd(&cursor[seg], 1);
    edge_list[row_start[seg] + pos] = make_int2(s, t);
}

// ---------------------------------------------------------------------------
// Gather: ONE WAVE per destination segment (avg degree ~2).
// lane = (h, q): h = lane>>4 (head), q = lane&15 (float4 quarter of d).
// One dwordx4 per lane fetches the whole 1KB M row coalesced.
// Flash-style single-pass online softmax, fully per-lane (no shuffles).
// Output written once, coalesced, ELU fused.
// ---------------------------------------------------------------------------
__global__ __launch_bounds__(256) void k_gather(
        const int2* __restrict__ edge_list, const int* __restrict__ row_start,
        const int* __restrict__ cnt,
        const float* __restrict__ M_a, const float* __restrict__ M_b,
        const float* __restrict__ mt_ab, const float* __restrict__ mt_ba,
        const float* __restrict__ ssrc_a, const float* __restrict__ ssrc_b,
        const float* __restrict__ sdst_a, const float* __restrict__ sdst_b,
        const float* __restrict__ st_ab, const float* __restrict__ st_ba,
        float* __restrict__ dout, int N) {
    int wid = (blockIdx.x * 256 + threadIdx.x) >> 6;   // wave id = segment
    if (wid >= 2 * N) return;
    int seg = wid;
    int lane = threadIdx.x & 63;
    int h = lane >> 4;
    bool isB = seg >= N;               // dst in b => direction ab, src = a
    int n = isB ? seg - N : seg;
    const float* M    = isB ? M_a    : M_b;
    const float* mt   = isB ? mt_ab  : mt_ba;
    const float* ssrc = isB ? ssrc_a : ssrc_b;
    const float* sdst = isB ? sdst_b : sdst_a;
    const float* st   = isB ? st_ab  : st_ba;
    int start = row_start[seg];
    int deg   = cnt[seg];
    float sd = sdst[n * HH + h];
    float m = -INFINITY, den = 0.f;
    float ax = 0.f, ay = 0.f, az = 0.f, aw = 0.f;
    for (int j = 0; j < deg; ++j) {
        int2 rec = edge_list[start + j];       // uniform -> scalar load
        int s = rec.x, t = rec.y;
        float l0 = ssrc[s * HH + h] + sd + st[t * HH + h];
        float l = l0 > 0.f ? l0 : NEG_SLOPE * l0;
        float nm = fmaxf(m, l);
        float sc = __expf(m - nm);             // first iter: exp(-inf)=0
        float w  = __expf(l - nm);
        den = den * sc + w;
        float4 Mv = *reinterpret_cast<const float4*>(M  + (size_t)s * (HH * DD) + lane * 4);
        float4 Tv = *reinterpret_cast<const float4*>(mt + (size_t)t * (HH * DD) + lane * 4);
        ax = ax * sc + w * (Mv.x + Tv.x);
        ay = ay * sc + w * (Mv.y + Tv.y);
        az = az * sc + w * (Mv.z + Tv.z);
        aw = aw * sc + w * (Mv.w + Tv.w);
        m = nm;
    }
    float inv = 1.f / (den + 1e-16f);
    float4 v;
    v.x = ax * inv; v.x = v.x > 0.f ? v.x : expm1f(v.x);
    v.y = ay * inv; v.y = v.y > 0.f ? v.y : expm1f(v.y);
    v.z = az * inv; v.z = v.z > 0.f ? v.z : expm1f(v.z);
    v.w = aw * inv; v.w = v.w > 0.f ? v.w : expm1f(v.w);
    *reinterpret_cast<float4*>(dout + (size_t)seg * (HH * DD) + lane * 4) = v;
}

// ---------------------------------------------------------------------------
extern "C" void kernel_launch(void* const* d_in, const int* in_sizes, int n_in,
                              void* d_out, int out_size, void* d_ws, size_t ws_size,
                              hipStream_t stream) {
    const float* x_a     = (const float*)d_in[0];
    const float* x_b     = (const float*)d_in[1];
    const float* W_a     = (const float*)d_in[2];
    const float* b_a     = (const float*)d_in[3];
    const float* W_b     = (const float*)d_in[4];
    const float* b_b     = (const float*)d_in[5];
    const float* te      = (const float*)d_in[6];
    const float* Wsrc_ab = (const float*)d_in[7];
    const float* Wdst_ab = (const float*)d_in[8];
    const float* asrc_ab = (const float*)d_in[9];
    const float* adst_ab = (const float*)d_in[10];
    const float* Wsrc_ba = (const float*)d_in[11];
    const float* Wdst_ba = (const float*)d_in[12];
    const float* asrc_ba = (const float*)d_in[13];
    const float* adst_ba = (const float*)d_in[14];
    const int*   ei_ab   = (const int*)d_in[15];
    const int*   et_ab   = (const int*)d_in[16];
    const int*   ei_ba   = (const int*)d_in[17];
    const int*   et_ba   = (const int*)d_in[18];
    float* dout = (float*)d_out;

    int N = in_sizes[0] / DD;
    int E = in_sizes[15] / 2;
    int V = in_sizes[6] / DD;
    int N2 = 2 * N;

    // workspace carve-up (256B aligned)
    char* p = (char*)d_ws;
    auto alloc = [&](size_t bytes) {
        char* r = p; p += (bytes + 255) & ~(size_t)255; return r;
    };
    float* M_a      = (float*)alloc((size_t)N * HH * DD * 4);
    float* M_b      = (float*)alloc((size_t)N * HH * DD * 4);
    float* ssrc_a   = (float*)alloc((size_t)N * HH * 4);
    float* sdst_a   = (float*)alloc((size_t)N * HH * 4);
    float* ssrc_b   = (float*)alloc((size_t)N * HH * 4);
    float* sdst_b   = (float*)alloc((size_t)N * HH * 4);
    float* st_ab    = (float*)alloc(V * HH * 4);
    float* st_ba    = (float*)alloc(V * HH * 4);
    float* mt_ab    = (float*)alloc(V * HH * DD * 4);
    float* mt_ba    = (float*)alloc(V * HH * DD * 4);
    float* Wc_a     = (float*)alloc(HH * DD * DD * 4);
    float* Wc_b     = (float*)alloc(HH * DD * DD * 4);
    float* bc_a     = (float*)alloc(HH * DD * 4);
    float* bc_b     = (float*)alloc(HH * DD * 4);
    float* wdst_a   = (float*)alloc(HH * DD * 4);
    float* wdst_b   = (float*)alloc(HH * DD * 4);
    float* bdst_a   = (float*)alloc(HH * 4);
    float* bdst_b   = (float*)alloc(HH * 4);
    float* ub_s_ab  = (float*)alloc(HH * DD * 4);
    float* ub_d_ab  = (float*)alloc(HH * DD * 4);
    float* ut_d_ab  = (float*)alloc(HH * DD * 4);
    float* ub_s_ba  = (float*)alloc(HH * DD * 4);
    float* ub_d_ba  = (float*)alloc(HH * DD * 4);
    float* ut_d_ba  = (float*)alloc(HH * DD * 4);
    int*   cnt      = (int*)alloc((size_t)N2 * 4);
    int*   cursor   = (int*)alloc((size_t)N2 * 4);
    int*   tmp      = (int*)alloc((size_t)N2 * 4);
    int*   row_start= (int*)alloc((size_t)N2 * 4);
    int*   bsum     = (int*)alloc(1024 * 4);
    int2*  edge_list= (int2*)alloc((size_t)2 * E * 8);

    // 1. fold weights
    k_fold_mats<<<(2 * HH * DD * DD + 255) / 256, 256, 0, stream>>>(
        W_a, Wsrc_ab, W_b, Wsrc_ba, Wc_a, Wc_b);
    k_fold_u<<<3, 256, 0, stream>>>(Wsrc_ab, asrc_ab, Wdst_ab, adst_ab,
                                    ub_s_ab, ub_d_ab, ut_d_ab);
    k_fold_u<<<3, 256, 0, stream>>>(Wsrc_ba, asrc_ba, Wdst_ba, adst_ba,
                                    ub_s_ba, ub_d_ba, ut_d_ba);
    int miscTot = V * HH * DD + HH * DD + V * HH + HH * DD + HH;
    int miscBlocks = (miscTot + 255) / 256;
    k_fold_misc<<<miscBlocks, 256, 0, stream>>>(
        b_a, Wsrc_ab, W_b, b_b, te, V, ub_s_ab, ub_d_ab, ut_d_ab,
        bc_a, st_ab, mt_ab, wdst_b, bdst_b);
    k_fold_misc<<<miscBlocks, 256, 0, stream>>>(
        b_b, Wsrc_ba, W_a, b_a, te, V, ub_s_ba, ub_d_ba, ut_d_ba,
        bc_b, st_ba, mt_ba, wdst_a, bdst_a);

    // 2. node transforms (M, ssrc, sdst) — 8-node ILP
    int ntBlocks = (N + 63) / 64;
    k_node_transform<<<ntBlocks, 256, 0, stream>>>(
        x_a, Wc_a, bc_a, asrc_ab, wdst_a, bdst_a, M_a, ssrc_a, sdst_a, N);
    k_node_transform<<<ntBlocks, 256, 0, stream>>>(
        x_b, Wc_b, bc_b, asrc_ba, wdst_b, bdst_b, M_b, ssrc_b, sdst_b, N);

    // 3. CSR build over combined 2N segment space
    k_zero<<<(N2 + 255) / 256, 256, 0, stream>>>(cnt, cursor, N2);
    k_count<<<(2 * E + 255) / 256, 256, 0, stream>>>(ei_ab, ei_ba, cnt, N, E);
    int nb = (N2 + 1023) / 1024;
    k_scan1<<<nb, 256, 0, stream>>>(cnt, tmp, bsum, N2);
    k_scan2<<<1, 256, 0, stream>>>(bsum, nb);
    k_scan3<<<(N2 + 255) / 256, 256, 0, stream>>>(tmp, cnt, bsum, row_start, N2);
    k_fill<<<(2 * E + 255) / 256, 256, 0, stream>>>(
        ei_ab, et_ab, ei_ba, et_ba, row_start, cursor, edge_list, N, E);

    // 4. one wave per segment: online softmax + gather + ELU
    k_gather<<<(N2 + 3) / 4, 256, 0, stream>>>(
        edge_list, row_start, cnt,
        M_a, M_b, mt_ab, mt_ba,
        ssrc_a, ssrc_b, sdst_a, sdst_b, st_ab, st_ba,
        dout, N);
}